// Round 1
// baseline (2665.050 us; speedup 1.0000x reference)
//
#include <hip/hip_runtime.h>
#include <math.h>

#define N_NODES 20000
#define E_EDGES 320000
#define DIN     256
#define HHD     512
#define HIDD    64
#define NHEADS  8
#define K1N     15000
#define K2N     11250

static inline int cdiv(long long a, long long b) { return (int)((a + b - 1) / b); }

__device__ __forceinline__ void atomicMaxF(float* addr, float val) {
  int* ai = (int*)addr;
  int old = __float_as_int(*addr);
  while (__int_as_float(old) < val) {
    int assumed = old;
    old = atomicCAS(ai, assumed, __float_as_int(val));
    if (old == assumed) break;
  }
}

__global__ void fill_f32(float* __restrict__ p, float v, int n) {
  int i = blockIdx.x * blockDim.x + threadIdx.x;
  if (i < n) p[i] = v;
}

// C[M,Nc] = A[M,K] @ W[K,Nc]; requires Nc % 64 == 0, K % 16 == 0; M bounds-checked.
__global__ __launch_bounds__(256) void gemm_f32(const float* __restrict__ A,
                                                const float* __restrict__ W,
                                                float* __restrict__ C,
                                                int M, int Nc, int K) {
  __shared__ float As[16][65];
  __shared__ float Ws[16][64];
  int tid = threadIdx.x;
  int tr = tid >> 4, tc = tid & 15;
  int brow = blockIdx.y * 64, bcol = blockIdx.x * 64;
  float acc[4][4] = {{0.f}};
  for (int k0 = 0; k0 < K; k0 += 16) {
    for (int i = tid; i < 64 * 16; i += 256) {
      int r = i >> 4, kk = i & 15;
      int gr = brow + r;
      As[kk][r] = (gr < M) ? A[(size_t)gr * K + k0 + kk] : 0.f;
    }
    for (int i = tid; i < 16 * 64; i += 256) {
      int kk = i >> 6, c = i & 63;
      Ws[kk][c] = W[(size_t)(k0 + kk) * Nc + bcol + c];
    }
    __syncthreads();
#pragma unroll
    for (int kk = 0; kk < 16; kk++) {
      float a[4], w[4];
#pragma unroll
      for (int u = 0; u < 4; u++) a[u] = As[kk][tr * 4 + u];
#pragma unroll
      for (int u = 0; u < 4; u++) w[u] = Ws[kk][tc * 4 + u];
#pragma unroll
      for (int u = 0; u < 4; u++)
#pragma unroll
        for (int v = 0; v < 4; v++) acc[u][v] += a[u] * w[v];
    }
    __syncthreads();
  }
  for (int u = 0; u < 4; u++) {
    int gr = brow + tr * 4 + u;
    if (gr < M)
      for (int v = 0; v < 4; v++)
        C[(size_t)gr * Nc + bcol + tc * 4 + v] = acc[u][v];
  }
}

// ---------------- Stage 1: GATv2 (D_IN->HID x 8 heads), one wave per edge ----------------
__global__ __launch_bounds__(256) void gat1_edge_scores(const int* __restrict__ src,
                                                        const int* __restrict__ dst,
                                                        const float* __restrict__ xl,
                                                        const float* __restrict__ xr,
                                                        const float* __restrict__ att,
                                                        float* __restrict__ eo,
                                                        float* __restrict__ mx) {
  int lane = threadIdx.x & 63;
  long long t = (long long)blockIdx.x * blockDim.x + threadIdx.x;
  int eid = (int)(t >> 6);
  if (eid >= E_EDGES + N_NODES) return;
  int s, d;
  if (eid < E_EDGES) { s = src[eid]; d = dst[eid]; } else { s = d = eid - E_EDGES; }
  const float* pl = xl + (size_t)s * HHD;
  const float* pr = xr + (size_t)d * HHD;
  float eh[NHEADS];
#pragma unroll
  for (int h = 0; h < NHEADS; h++) {
    int c = (h << 6) + lane;
    float v = pl[c] + pr[c];
    v = v > 0.f ? v : 0.2f * v;           // LeakyReLU(0.2)
    eh[h] = v * att[c];                    // att row-major (8,64)
  }
#pragma unroll
  for (int h = 0; h < NHEADS; h++) {
    float v = eh[h];
#pragma unroll
    for (int off = 32; off > 0; off >>= 1) v += __shfl_xor(v, off);
    eh[h] = v;
  }
  if (lane == 0) {
#pragma unroll
    for (int h = 0; h < NHEADS; h++) {
      eo[(size_t)eid * NHEADS + h] = eh[h];
      atomicMaxF(&mx[d * NHEADS + h], eh[h]);
    }
  }
}

__global__ __launch_bounds__(256) void gat1_expden(const int* __restrict__ dst,
                                                   float* __restrict__ e,
                                                   const float* __restrict__ mx,
                                                   float* __restrict__ den) {
  long long i = (long long)blockIdx.x * blockDim.x + threadIdx.x;
  if (i >= (long long)(E_EDGES + N_NODES) * NHEADS) return;
  int eid = (int)(i / NHEADS), h = (int)(i % NHEADS);
  int d = eid < E_EDGES ? dst[eid] : eid - E_EDGES;
  float ex = expf(e[i] - mx[d * NHEADS + h]);
  e[i] = ex;
  atomicAdd(&den[d * NHEADS + h], ex);
}

__global__ __launch_bounds__(256) void gat1_aggregate(const int* __restrict__ src,
                                                      const int* __restrict__ dst,
                                                      const float* __restrict__ xl,
                                                      const float* __restrict__ e,
                                                      const float* __restrict__ den,
                                                      float* __restrict__ out) {
  int lane = threadIdx.x & 63;
  long long t = (long long)blockIdx.x * blockDim.x + threadIdx.x;
  int eid = (int)(t >> 6);
  if (eid >= E_EDGES + N_NODES) return;
  int s, d;
  if (eid < E_EDGES) { s = src[eid]; d = dst[eid]; } else { s = d = eid - E_EDGES; }
  const float* pl = xl + (size_t)s * HHD;
  float* po = out + (size_t)d * HHD;
#pragma unroll
  for (int h = 0; h < NHEADS; h++) {
    float a = e[(size_t)eid * NHEADS + h] / den[d * NHEADS + h];
    int c = (h << 6) + lane;
    atomicAdd(&po[c], a * pl[c]);
  }
}

__global__ void bias_relu(float* __restrict__ h, const float* __restrict__ b,
                          long long n, int c) {
  long long i = (long long)blockIdx.x * blockDim.x + threadIdx.x;
  if (i < n) {
    float v = h[i] + b[i % c];
    h[i] = v > 0.f ? v : 0.f;
  }
}

// ---------------- scalar GATConv scoring (pool layers), one wave per node for proj ----------------
__global__ __launch_bounds__(256) void proj_dot(const float* __restrict__ x,
                                                const float* __restrict__ w,
                                                float* __restrict__ o, int n, int F) {
  int lane = threadIdx.x & 63;
  long long t = (long long)blockIdx.x * blockDim.x + threadIdx.x;
  int i = (int)(t >> 6);
  if (i >= n) return;
  float s = 0.f;
  for (int c = lane; c < F; c += 64) s += x[(size_t)i * F + c] * w[c];
#pragma unroll
  for (int off = 32; off > 0; off >>= 1) s += __shfl_xor(s, off);
  if (lane == 0) o[i] = s;
}

__global__ void sc_edge_scores(const int* __restrict__ src, const int* __restrict__ dst,
                               const int* __restrict__ newid,
                               const float* __restrict__ xls,
                               const float* __restrict__ asrc, const float* __restrict__ adst,
                               float* __restrict__ es, float* __restrict__ mxs, int nloops) {
  int i = blockIdx.x * blockDim.x + threadIdx.x;
  if (i >= E_EDGES + nloops) return;
  int s, d;
  if (i < E_EDGES) {
    s = src[i]; d = dst[i];
    if (newid) { s = newid[s]; d = newid[d]; if (s < 0 || d < 0) return; }
  } else { s = d = i - E_EDGES; }
  float e = xls[s] * asrc[0] + xls[d] * adst[0];
  e = e > 0.f ? e : 0.2f * e;
  es[i] = e;
  atomicMaxF(&mxs[d], e);
}

__global__ void sc_expden(const int* __restrict__ src, const int* __restrict__ dst,
                          const int* __restrict__ newid,
                          float* __restrict__ es, const float* __restrict__ mxs,
                          float* __restrict__ dens, int nloops) {
  int i = blockIdx.x * blockDim.x + threadIdx.x;
  if (i >= E_EDGES + nloops) return;
  int s, d;
  if (i < E_EDGES) {
    s = src[i]; d = dst[i];
    if (newid) { s = newid[s]; d = newid[d]; if (s < 0 || d < 0) return; }
  } else { s = d = i - E_EDGES; }
  float ex = expf(es[i] - mxs[d]);
  es[i] = ex;
  atomicAdd(&dens[d], ex);
}

__global__ void sc_aggregate(const int* __restrict__ src, const int* __restrict__ dst,
                             const int* __restrict__ newid,
                             const float* __restrict__ xls, const float* __restrict__ es,
                             const float* __restrict__ dens, float* __restrict__ attn,
                             int nloops) {
  int i = blockIdx.x * blockDim.x + threadIdx.x;
  if (i >= E_EDGES + nloops) return;
  int s, d;
  if (i < E_EDGES) {
    s = src[i]; d = dst[i];
    if (newid) { s = newid[s]; d = newid[d]; if (s < 0 || d < 0) return; }
  } else { s = d = i - E_EDGES; }
  atomicAdd(&attn[d], (es[i] / dens[d]) * xls[s]);
}

__global__ void tanh_score(const float* __restrict__ attn, const float* __restrict__ b,
                           const float* __restrict__ sel, float* __restrict__ score, int n) {
  int i = blockIdx.x * blockDim.x + threadIdx.x;
  if (i < n) {
    float s = sel[0];
    score[i] = tanhf((attn[i] + b[0]) * s / fabsf(s));
  }
}

// rank-based exact top-k selection (matches jax.lax.top_k incl. tie-break by index)
__global__ __launch_bounds__(256) void topk_rank(const float* __restrict__ score,
                                                 int* __restrict__ newid, int n, int k) {
  __shared__ float sc[2048];
  int i = blockIdx.x * blockDim.x + threadIdx.x;
  float si = (i < n) ? score[i] : 0.f;
  int rank = 0;
  for (int base = 0; base < n; base += 2048) {
    int cnt = min(2048, n - base);
    __syncthreads();
    for (int j = threadIdx.x; j < cnt; j += blockDim.x) sc[j] = score[base + j];
    __syncthreads();
    if (i < n) {
      for (int j = 0; j < cnt; j++) {
        float sj = sc[j];
        rank += (sj > si) || ((sj == si) && ((base + j) < i));
      }
    }
  }
  if (i < n) newid[i] = (rank < k) ? rank : -1;
}

__global__ void pool_features(const float* __restrict__ h, const float* __restrict__ score,
                              const int* __restrict__ newid, float* __restrict__ hp,
                              int n, int F) {
  long long i = (long long)blockIdx.x * blockDim.x + threadIdx.x;
  if (i >= (long long)n * F) return;
  int node = (int)(i / F), c = (int)(i % F);
  int nid = newid[node];
  if (nid < 0) return;
  hp[(size_t)nid * F + c] = h[i] * score[node];
}

// ---------------- Stage 2: GATv2 heads=1, dim 64; edges mapped through newid ----------------
__global__ __launch_bounds__(256) void gat2_edge_scores(const int* __restrict__ src,
                                                        const int* __restrict__ dst,
                                                        const int* __restrict__ newid,
                                                        const float* __restrict__ xl,
                                                        const float* __restrict__ xr,
                                                        const float* __restrict__ att,
                                                        float* __restrict__ eo,
                                                        float* __restrict__ mx, int nloops) {
  int lane = threadIdx.x & 63;
  long long t = (long long)blockIdx.x * blockDim.x + threadIdx.x;
  int eid = (int)(t >> 6);
  if (eid >= E_EDGES + nloops) return;
  int s, d;
  if (eid < E_EDGES) {
    s = newid[src[eid]]; d = newid[dst[eid]];
    if (s < 0 || d < 0) return;
  } else { s = d = eid - E_EDGES; }
  float v = xl[(size_t)s * HIDD + lane] + xr[(size_t)d * HIDD + lane];
  v = v > 0.f ? v : 0.2f * v;
  v *= att[lane];
#pragma unroll
  for (int off = 32; off > 0; off >>= 1) v += __shfl_xor(v, off);
  if (lane == 0) {
    eo[eid] = v;
    atomicMaxF(&mx[d], v);
  }
}

__global__ __launch_bounds__(256) void gat2_aggregate(const int* __restrict__ src,
                                                      const int* __restrict__ dst,
                                                      const int* __restrict__ newid,
                                                      const float* __restrict__ xl,
                                                      const float* __restrict__ e,
                                                      const float* __restrict__ den,
                                                      float* __restrict__ out, int nloops) {
  int lane = threadIdx.x & 63;
  long long t = (long long)blockIdx.x * blockDim.x + threadIdx.x;
  int eid = (int)(t >> 6);
  if (eid >= E_EDGES + nloops) return;
  int s, d;
  if (eid < E_EDGES) {
    s = newid[src[eid]]; d = newid[dst[eid]];
    if (s < 0 || d < 0) return;
  } else { s = d = eid - E_EDGES; }
  float a = e[eid] / den[d];
  atomicAdd(&out[(size_t)d * HIDD + lane], a * xl[(size_t)s * HIDD + lane]);
}

__global__ void col_max_mean(const float* __restrict__ X, int rows, int cols,
                             float* __restrict__ omax, float* __restrict__ omean) {
  int c = blockIdx.x;
  int tid = threadIdx.x;
  float mx = -INFINITY, sm = 0.f;
  for (int r = tid; r < rows; r += blockDim.x) {
    float v = X[(size_t)r * cols + c];
    mx = fmaxf(mx, v);
    sm += v;
  }
  __shared__ float smx[256], ssm[256];
  smx[tid] = mx; ssm[tid] = sm;
  __syncthreads();
  for (int s = 128; s > 0; s >>= 1) {
    if (tid < s) { smx[tid] = fmaxf(smx[tid], smx[tid + s]); ssm[tid] += ssm[tid + s]; }
    __syncthreads();
  }
  if (tid == 0) { omax[c] = smx[0]; omean[c] = ssm[0] / rows; }
}

__global__ __launch_bounds__(512) void mlp_head(const float* __restrict__ x1max,
                                                const float* __restrict__ x1mean,
                                                const float* __restrict__ g2max,
                                                const float* __restrict__ g2mean,
                                                const float* __restrict__ w1, const float* __restrict__ b1,
                                                const float* __restrict__ w2, const float* __restrict__ b2,
                                                const float* __restrict__ w3, const float* __restrict__ b3,
                                                const float* __restrict__ w4, const float* __restrict__ b4,
                                                float* __restrict__ out) {
  __shared__ float z[1024], z1[512], z2[256], z3[128], lg[2];
  int tid = threadIdx.x;
  for (int i = tid; i < 1024; i += 512) {
    float xv = (i < 512) ? x1max[i] : x1mean[i - 512];
    float gv = (i < 512) ? g2max[i & 63] : g2mean[i & 63];
    z[i] = xv + gv;
  }
  __syncthreads();
  {
    float acc = b1[tid];
    for (int k = 0; k < 1024; k++) acc += z[k] * w1[k * 512 + tid];
    z1[tid] = acc > 0.f ? acc : 0.f;
  }
  __syncthreads();
  if (tid < 256) {
    float acc = b2[tid];
    for (int k = 0; k < 512; k++) acc += z1[k] * w2[k * 256 + tid];
    z2[tid] = acc > 0.f ? acc : 0.f;
  }
  __syncthreads();
  if (tid < 128) {
    float acc = b3[tid];
    for (int k = 0; k < 256; k++) acc += z2[k] * w3[k * 128 + tid];
    z3[tid] = acc > 0.f ? acc : 0.f;
  }
  __syncthreads();
  if (tid < 2) {
    float acc = b4[tid];
    for (int k = 0; k < 128; k++) acc += z3[k] * w4[k * 2 + tid];
    lg[tid] = acc;
  }
  __syncthreads();
  if (tid == 0) {
    float m = fmaxf(lg[0], lg[1]);
    float e0 = expf(lg[0] - m), e1 = expf(lg[1] - m);
    float s = e0 + e1;
    out[0] = lg[0]; out[1] = lg[1];
    out[2] = e0 / s; out[3] = e1 / s;
  }
}

extern "C" void kernel_launch(void* const* d_in, const int* in_sizes, int n_in,
                              void* d_out, int out_size, void* d_ws, size_t ws_size,
                              hipStream_t stream) {
  const float* x       = (const float*)d_in[0];
  const int*   ei      = (const int*)d_in[1];
  const float* g1_wl   = (const float*)d_in[2];
  const float* g1_wr   = (const float*)d_in[3];
  const float* g1_att  = (const float*)d_in[4];
  const float* g1_b    = (const float*)d_in[5];
  const float* p1_w    = (const float*)d_in[6];
  const float* p1_asrc = (const float*)d_in[7];
  const float* p1_adst = (const float*)d_in[8];
  const float* p1_b    = (const float*)d_in[9];
  const float* p1_sel  = (const float*)d_in[10];
  const float* g2_wl   = (const float*)d_in[11];
  const float* g2_wr   = (const float*)d_in[12];
  const float* g2_att  = (const float*)d_in[13];
  const float* g2_b    = (const float*)d_in[14];
  const float* p2_w    = (const float*)d_in[15];
  const float* p2_asrc = (const float*)d_in[16];
  const float* p2_adst = (const float*)d_in[17];
  const float* p2_b    = (const float*)d_in[18];
  const float* p2_sel  = (const float*)d_in[19];
  const float* l1_w    = (const float*)d_in[20];
  const float* l1_b    = (const float*)d_in[21];
  const float* l2_w    = (const float*)d_in[22];
  const float* l2_b    = (const float*)d_in[23];
  const float* l3_w    = (const float*)d_in[24];
  const float* l3_b    = (const float*)d_in[25];
  const float* l4_w    = (const float*)d_in[26];
  const float* l4_b    = (const float*)d_in[27];

  const int* src = ei;
  const int* dst = ei + E_EDGES;

  // ---- workspace arena (floats), lifetime-aliased; total 33,800,000 f32 = 135.2 MB ----
  if (ws_size < (size_t)33800000 * 4) return;  // fail loudly (wrong output) rather than corrupt
  float* ws  = (float*)d_ws;
  float* xl1 = ws;                 // 10,240,000   (later: hp1)
  float* xr1 = ws + 10240000;      // 10,240,000   (later: stage-2 arena)
  float* h1  = ws + 20480000;      // 10,240,000
  float* e1  = ws + 30720000;      //  2,720,000   (later: pool-1 scoring arena)
  float* r4  = ws + 33440000;      //    360,000   small persistents

  float* mx1    = r4;
  float* den1   = r4 + 160000;
  int*   newid1 = (int*)(r4 + 320000);
  int*   newid2 = (int*)(r4 + 340000);
  float* x1max  = r4 + 355000;
  float* x1mean = r4 + 355512;
  float* g2max  = r4 + 356024;
  float* g2mean = r4 + 356088;

  // pool-1 scoring arena (reuses e1 after stage-1 aggregation)
  float* xls1  = e1;
  float* es1   = e1 + 20000;
  float* mxs1  = e1 + 360000;
  float* dens1 = e1 + 380000;
  float* attn1 = e1 + 400000;
  float* scr1  = e1 + 420000;

  // stage-2 arena (reuses xr1 after stage-1 edge scores)
  float* xl2   = xr1;
  float* xr2   = xr1 + 960000;
  float* h2    = xr1 + 1920000;
  float* e2    = xr1 + 2880000;
  float* mx2   = xr1 + 3215000;
  float* den2  = xr1 + 3230000;
  float* xls2  = xr1 + 3245000;
  float* es2   = xr1 + 3260000;
  float* mxs2  = xr1 + 3595000;
  float* dens2 = xr1 + 3610000;
  float* attn2 = xr1 + 3625000;
  float* scr2  = xr1 + 3640000;
  float* hp2   = xr1 + 3655000;
  float* hp1   = xl1;

  dim3 b256(256);
  const int E1 = E_EDGES + N_NODES;   // 340000 (edges + self loops, stage 1)
  const int E2 = E_EDGES + K1N;       // 335000 (edges + self loops, stage 2)

  // ---- Stage 1: GATv2 (x -> h1), 8 heads x 64 ----
  gemm_f32<<<dim3(8, 313), b256, 0, stream>>>(x, g1_wl, xl1, N_NODES, HHD, DIN);
  gemm_f32<<<dim3(8, 313), b256, 0, stream>>>(x, g1_wr, xr1, N_NODES, HHD, DIN);
  fill_f32<<<cdiv(160000, 256), b256, 0, stream>>>(mx1, -INFINITY, 160000);
  fill_f32<<<cdiv(160000, 256), b256, 0, stream>>>(den1, 0.f, 160000);
  fill_f32<<<cdiv(10240000, 256), b256, 0, stream>>>(h1, 0.f, 10240000);
  gat1_edge_scores<<<cdiv((long long)E1 * 64, 256), b256, 0, stream>>>(src, dst, xl1, xr1, g1_att, e1, mx1);
  gat1_expden<<<cdiv((long long)E1 * 8, 256), b256, 0, stream>>>(dst, e1, mx1, den1);
  gat1_aggregate<<<cdiv((long long)E1 * 64, 256), b256, 0, stream>>>(src, dst, xl1, e1, den1, h1);
  bias_relu<<<cdiv(10240000, 256), b256, 0, stream>>>(h1, g1_b, 10240000LL, HHD);

  // ---- Pool 1: GATConv score -> tanh -> top-k -> gather ----
  proj_dot<<<cdiv((long long)N_NODES * 64, 256), b256, 0, stream>>>(h1, p1_w, xls1, N_NODES, HHD);
  fill_f32<<<cdiv(N_NODES, 256), b256, 0, stream>>>(mxs1, -INFINITY, N_NODES);
  fill_f32<<<cdiv(N_NODES, 256), b256, 0, stream>>>(dens1, 0.f, N_NODES);
  fill_f32<<<cdiv(N_NODES, 256), b256, 0, stream>>>(attn1, 0.f, N_NODES);
  sc_edge_scores<<<cdiv(E1, 256), b256, 0, stream>>>(src, dst, nullptr, xls1, p1_asrc, p1_adst, es1, mxs1, N_NODES);
  sc_expden<<<cdiv(E1, 256), b256, 0, stream>>>(src, dst, nullptr, es1, mxs1, dens1, N_NODES);
  sc_aggregate<<<cdiv(E1, 256), b256, 0, stream>>>(src, dst, nullptr, xls1, es1, dens1, attn1, N_NODES);
  tanh_score<<<cdiv(N_NODES, 256), b256, 0, stream>>>(attn1, p1_b, p1_sel, scr1, N_NODES);
  topk_rank<<<cdiv(N_NODES, 256), b256, 0, stream>>>(scr1, newid1, N_NODES, K1N);
  pool_features<<<cdiv((long long)N_NODES * HHD, 256), b256, 0, stream>>>(h1, scr1, newid1, hp1, N_NODES, HHD);
  col_max_mean<<<HHD, b256, 0, stream>>>(hp1, K1N, HHD, x1max, x1mean);

  // ---- Stage 2: GATv2 (hp1 -> h2), 1 head x 64 ----
  gemm_f32<<<dim3(1, cdiv(K1N, 64)), b256, 0, stream>>>(hp1, g2_wl, xl2, K1N, HIDD, HHD);
  gemm_f32<<<dim3(1, cdiv(K1N, 64)), b256, 0, stream>>>(hp1, g2_wr, xr2, K1N, HIDD, HHD);
  fill_f32<<<cdiv(960000, 256), b256, 0, stream>>>(h2, 0.f, 960000);
  fill_f32<<<cdiv(K1N, 256), b256, 0, stream>>>(mx2, -INFINITY, K1N);
  fill_f32<<<cdiv(K1N, 256), b256, 0, stream>>>(den2, 0.f, K1N);
  gat2_edge_scores<<<cdiv((long long)E2 * 64, 256), b256, 0, stream>>>(src, dst, newid1, xl2, xr2, g2_att, e2, mx2, K1N);
  sc_expden<<<cdiv(E2, 256), b256, 0, stream>>>(src, dst, newid1, e2, mx2, den2, K1N);
  gat2_aggregate<<<cdiv((long long)E2 * 64, 256), b256, 0, stream>>>(src, dst, newid1, xl2, e2, den2, h2, K1N);
  bias_relu<<<cdiv(960000, 256), b256, 0, stream>>>(h2, g2_b, 960000LL, HIDD);

  // ---- Pool 2 ----
  proj_dot<<<cdiv((long long)K1N * 64, 256), b256, 0, stream>>>(h2, p2_w, xls2, K1N, HIDD);
  fill_f32<<<cdiv(K1N, 256), b256, 0, stream>>>(mxs2, -INFINITY, K1N);
  fill_f32<<<cdiv(K1N, 256), b256, 0, stream>>>(dens2, 0.f, K1N);
  fill_f32<<<cdiv(K1N, 256), b256, 0, stream>>>(attn2, 0.f, K1N);
  sc_edge_scores<<<cdiv(E2, 256), b256, 0, stream>>>(src, dst, newid1, xls2, p2_asrc, p2_adst, es2, mxs2, K1N);
  sc_expden<<<cdiv(E2, 256), b256, 0, stream>>>(src, dst, newid1, es2, mxs2, dens2, K1N);
  sc_aggregate<<<cdiv(E2, 256), b256, 0, stream>>>(src, dst, newid1, xls2, es2, dens2, attn2, K1N);
  tanh_score<<<cdiv(K1N, 256), b256, 0, stream>>>(attn2, p2_b, p2_sel, scr2, K1N);
  topk_rank<<<cdiv(K1N, 256), b256, 0, stream>>>(scr2, newid2, K1N, K2N);
  pool_features<<<cdiv((long long)K1N * HIDD, 256), b256, 0, stream>>>(h2, scr2, newid2, hp2, K1N, HIDD);
  col_max_mean<<<HIDD, b256, 0, stream>>>(hp2, K2N, HIDD, g2max, g2mean);

  // ---- Readout + MLP head ----
  mlp_head<<<1, 512, 0, stream>>>(x1max, x1mean, g2max, g2mean,
                                  l1_w, l1_b, l2_w, l2_b, l3_w, l3_b, l4_w, l4_b,
                                  (float*)d_out);
}

// Round 2
// 1256.436 us; speedup vs baseline: 2.1211x; 2.1211x over previous
//
#include <hip/hip_runtime.h>
#include <math.h>

#define N_NODES 20000
#define E_EDGES 320000
#define DIN     256
#define HHD     512
#define HIDD    64
#define NHEADS  8
#define K1N     15000
#define K2N     11250

static inline int cdiv(long long a, long long b) { return (int)((a + b - 1) / b); }

__global__ void fill_i32(int* p, int v, int n) {
  int i = blockIdx.x * blockDim.x + threadIdx.x;
  if (i < n) p[i] = v;
}

// C[M,Nc] = A[M,K] @ W[K,Nc]; requires Nc % 64 == 0, K % 16 == 0; M bounds-checked.
__global__ __launch_bounds__(256) void gemm_f32(const float* __restrict__ A,
                                                const float* __restrict__ W,
                                                float* __restrict__ C,
                                                int M, int Nc, int K) {
  __shared__ float As[16][65];
  __shared__ float Ws[16][64];
  int tid = threadIdx.x;
  int tr = tid >> 4, tc = tid & 15;
  int brow = blockIdx.y * 64, bcol = blockIdx.x * 64;
  float acc[4][4] = {{0.f}};
  for (int k0 = 0; k0 < K; k0 += 16) {
    for (int i = tid; i < 64 * 16; i += 256) {
      int r = i >> 4, kk = i & 15;
      int gr = brow + r;
      As[kk][r] = (gr < M) ? A[(size_t)gr * K + k0 + kk] : 0.f;
    }
    for (int i = tid; i < 16 * 64; i += 256) {
      int kk = i >> 6, c = i & 63;
      Ws[kk][c] = W[(size_t)(k0 + kk) * Nc + bcol + c];
    }
    __syncthreads();
#pragma unroll
    for (int kk = 0; kk < 16; kk++) {
      float a[4], w[4];
#pragma unroll
      for (int u = 0; u < 4; u++) a[u] = As[kk][tr * 4 + u];
#pragma unroll
      for (int u = 0; u < 4; u++) w[u] = Ws[kk][tc * 4 + u];
#pragma unroll
      for (int u = 0; u < 4; u++)
#pragma unroll
        for (int v = 0; v < 4; v++) acc[u][v] += a[u] * w[v];
    }
    __syncthreads();
  }
  for (int u = 0; u < 4; u++) {
    int gr = brow + tr * 4 + u;
    if (gr < M)
      for (int v = 0; v < 4; v++)
        C[(size_t)gr * Nc + bcol + tc * 4 + v] = acc[u][v];
  }
}

// ---------------- CSR construction ----------------
// degree count; newid==nullptr -> stage-1 (all E edges valid, nloops self loops),
// else stage-2 (remap via newid, skip invalid).
__global__ void deg_count(const int* __restrict__ src, const int* __restrict__ dst,
                          const int* __restrict__ newid, int* __restrict__ deg,
                          int nloops) {
  int i = blockIdx.x * blockDim.x + threadIdx.x;
  if (i >= E_EDGES + nloops) return;
  int d;
  if (i < E_EDGES) {
    if (newid) {
      int s = newid[src[i]]; d = newid[dst[i]];
      if (s < 0 || d < 0) return;
    } else d = dst[i];
  } else d = i - E_EDGES;
  atomicAdd(&deg[d], 1);
}

// single-block exclusive scan: rowptr[0..n] and cursor[i]=rowptr[i].
// NOTE: cursor may alias deg (read-before-write within each tile).
__global__ __launch_bounds__(1024) void scan_excl(const int* deg, int* rowptr,
                                                  int* cursor, int n) {
  __shared__ int buf[1024];
  __shared__ int carry;
  int tid = threadIdx.x;
  if (tid == 0) { carry = 0; rowptr[0] = 0; }
  __syncthreads();
  for (int base = 0; base < n; base += 1024) {
    int v = (base + tid < n) ? deg[base + tid] : 0;
    buf[tid] = v;
    __syncthreads();
    for (int off = 1; off < 1024; off <<= 1) {
      int t = (tid >= off) ? buf[tid - off] : 0;
      __syncthreads();
      buf[tid] += t;
      __syncthreads();
    }
    int incl = buf[tid] + carry;
    if (base + tid < n) { rowptr[base + tid + 1] = incl; cursor[base + tid] = incl - v; }
    __syncthreads();
    if (tid == 1023) carry = incl;
    __syncthreads();
  }
}

__global__ void csr_scatter(const int* __restrict__ src, const int* __restrict__ dst,
                            const int* __restrict__ newid, int* __restrict__ cursor,
                            int* __restrict__ csr_eid, int nloops) {
  int i = blockIdx.x * blockDim.x + threadIdx.x;
  if (i >= E_EDGES + nloops) return;
  int d;
  if (i < E_EDGES) {
    if (newid) {
      int s = newid[src[i]]; d = newid[dst[i]];
      if (s < 0 || d < 0) return;
    } else d = dst[i];
  } else d = i - E_EDGES;
  int pos = atomicAdd(&cursor[d], 1);
  csr_eid[pos] = i;
}

// ---------------- Stage 1: GATv2 (D_IN->HID x 8 heads) ----------------
// per-edge raw scores (wave per edge), no atomics
__global__ __launch_bounds__(256) void gat1_edge_scores(const int* __restrict__ src,
                                                        const int* __restrict__ dst,
                                                        const float* __restrict__ xl,
                                                        const float* __restrict__ xr,
                                                        const float* __restrict__ att,
                                                        float* __restrict__ eo) {
  int lane = threadIdx.x & 63;
  long long t = (long long)blockIdx.x * blockDim.x + threadIdx.x;
  int eid = (int)(t >> 6);
  if (eid >= E_EDGES + N_NODES) return;
  int s, d;
  if (eid < E_EDGES) { s = src[eid]; d = dst[eid]; } else { s = d = eid - E_EDGES; }
  const float* pl = xl + (size_t)s * HHD;
  const float* pr = xr + (size_t)d * HHD;
  float eh[NHEADS];
#pragma unroll
  for (int h = 0; h < NHEADS; h++) {
    int c = (h << 6) + lane;
    float v = pl[c] + pr[c];
    v = v > 0.f ? v : 0.2f * v;
    eh[h] = v * att[c];
  }
#pragma unroll
  for (int h = 0; h < NHEADS; h++) {
    float v = eh[h];
#pragma unroll
    for (int off = 32; off > 0; off >>= 1) v += __shfl_xor(v, off);
    eh[h] = v;
  }
  if (lane == 0) {
#pragma unroll
    for (int h = 0; h < NHEADS; h++) eo[(size_t)eid * NHEADS + h] = eh[h];
  }
}

// per (dst,head) softmax normalization in place: e <- exp(e-max)/den
__global__ __launch_bounds__(256) void seg_softmax8(const int* __restrict__ rowptr,
                                                    const int* __restrict__ csr_eid,
                                                    float* __restrict__ e, int n) {
  int idx = blockIdx.x * blockDim.x + threadIdx.x;
  if (idx >= n * NHEADS) return;
  int d = idx >> 3, h = idx & 7;
  int b0 = rowptr[d], b1 = rowptr[d + 1];
  float m = -INFINITY;
  for (int j = b0; j < b1; j++) m = fmaxf(m, e[(size_t)csr_eid[j] * NHEADS + h]);
  float den = 0.f;
  for (int j = b0; j < b1; j++) den += expf(e[(size_t)csr_eid[j] * NHEADS + h] - m);
  float inv = 1.f / den;
  for (int j = b0; j < b1; j++) {
    size_t p = (size_t)csr_eid[j] * NHEADS + h;
    e[p] = expf(e[p] - m) * inv;
  }
}

// wave per dst node: register accumulation, bias+relu fused
__global__ __launch_bounds__(256) void gat1_agg_csr(const int* __restrict__ rowptr,
                                                    const int* __restrict__ csr_eid,
                                                    const int* __restrict__ src,
                                                    const float* __restrict__ alpha,
                                                    const float* __restrict__ xl,
                                                    const float* __restrict__ bias,
                                                    float* __restrict__ out) {
  int lane = threadIdx.x & 63;
  long long t = (long long)blockIdx.x * blockDim.x + threadIdx.x;
  int d = (int)(t >> 6);
  if (d >= N_NODES) return;
  int b0 = rowptr[d], b1 = rowptr[d + 1];
  float acc[NHEADS] = {0.f};
  for (int j = b0; j < b1; j++) {
    int eid = csr_eid[j];
    int s = (eid < E_EDGES) ? src[eid] : eid - E_EDGES;
    const float* pl = xl + (size_t)s * HHD;
    const float* pa = alpha + (size_t)eid * NHEADS;
#pragma unroll
    for (int h = 0; h < NHEADS; h++) acc[h] += pa[h] * pl[(h << 6) + lane];
  }
#pragma unroll
  for (int h = 0; h < NHEADS; h++) {
    int c = (h << 6) + lane;
    float v = acc[h] + bias[c];
    out[(size_t)d * HHD + c] = v > 0.f ? v : 0.f;
  }
}

// ---------------- pool scoring (GATConv -> 1), fused 2-pass + tanh ----------------
__global__ __launch_bounds__(256) void proj_dot(const float* __restrict__ x,
                                                const float* __restrict__ w,
                                                float* __restrict__ o, int n, int F) {
  int lane = threadIdx.x & 63;
  long long t = (long long)blockIdx.x * blockDim.x + threadIdx.x;
  int i = (int)(t >> 6);
  if (i >= n) return;
  float s = 0.f;
  for (int c = lane; c < F; c += 64) s += x[(size_t)i * F + c] * w[c];
#pragma unroll
  for (int off = 32; off > 0; off >>= 1) s += __shfl_xor(s, off);
  if (lane == 0) o[i] = s;
}

__global__ __launch_bounds__(256) void pool_score(const int* __restrict__ rowptr,
                                                  const int* __restrict__ csr_eid,
                                                  const int* __restrict__ src,
                                                  const int* __restrict__ newid_map,
                                                  const float* __restrict__ xls,
                                                  const float* __restrict__ asrc,
                                                  const float* __restrict__ adst,
                                                  const float* __restrict__ bias,
                                                  const float* __restrict__ sel,
                                                  float* __restrict__ score, int n) {
  int d = blockIdx.x * blockDim.x + threadIdx.x;
  if (d >= n) return;
  float as = asrc[0], ad = adst[0];
  float ar = xls[d] * ad;
  int b0 = rowptr[d], b1 = rowptr[d + 1];
  float m = -INFINITY;
  for (int j = b0; j < b1; j++) {
    int eid = csr_eid[j];
    int s = (eid < E_EDGES) ? (newid_map ? newid_map[src[eid]] : src[eid]) : eid - E_EDGES;
    float e = xls[s] * as + ar;
    e = e > 0.f ? e : 0.2f * e;
    m = fmaxf(m, e);
  }
  float den = 0.f, num = 0.f;
  for (int j = b0; j < b1; j++) {
    int eid = csr_eid[j];
    int s = (eid < E_EDGES) ? (newid_map ? newid_map[src[eid]] : src[eid]) : eid - E_EDGES;
    float xs = xls[s];
    float e = xs * as + ar;
    e = e > 0.f ? e : 0.2f * e;
    float ex = expf(e - m);
    den += ex; num += ex * xs;
  }
  float attn = num / den + bias[0];
  float sv = sel[0];
  score[d] = tanhf(attn * sv / fabsf(sv));
}

// ---------------- top-k via 2D-grid rank counting ----------------
#define TK_CHUNK 512
__global__ __launch_bounds__(256) void topk_count(const float* __restrict__ score,
                                                  int* __restrict__ rank, int n) {
  __shared__ float sc[TK_CHUNK];
  int i = blockIdx.x * 256 + threadIdx.x;
  int base = blockIdx.y * TK_CHUNK;
  int cnt = min(TK_CHUNK, n - base);
  for (int j = threadIdx.x; j < cnt; j += 256) sc[j] = score[base + j];
  __syncthreads();
  if (i >= n) return;
  float si = score[i];
  int r = 0;
  for (int j = 0; j < cnt; j++) {
    float sj = sc[j];
    r += (sj > si) || ((sj == si) && ((base + j) < i));
  }
  if (r) atomicAdd(&rank[i], r);
}

__global__ void topk_assign(const int* __restrict__ rank, int* __restrict__ newid,
                            int n, int k) {
  int i = blockIdx.x * blockDim.x + threadIdx.x;
  if (i < n) newid[i] = (rank[i] < k) ? rank[i] : -1;
}

__global__ void pool_features(const float* __restrict__ h, const float* __restrict__ score,
                              const int* __restrict__ newid, float* __restrict__ hp,
                              int n, int F) {
  long long i = (long long)blockIdx.x * blockDim.x + threadIdx.x;
  if (i >= (long long)n * F) return;
  int node = (int)(i / F), c = (int)(i % F);
  int nid = newid[node];
  if (nid < 0) return;
  hp[(size_t)nid * F + c] = h[i] * score[node];
}

// ---------------- Stage 2: GATv2 heads=1, dim 64 ----------------
__global__ __launch_bounds__(256) void gat2_edge_scores(const int* __restrict__ src,
                                                        const int* __restrict__ dst,
                                                        const int* __restrict__ newid,
                                                        const float* __restrict__ xl,
                                                        const float* __restrict__ xr,
                                                        const float* __restrict__ att,
                                                        float* __restrict__ eo, int nloops) {
  int lane = threadIdx.x & 63;
  long long t = (long long)blockIdx.x * blockDim.x + threadIdx.x;
  int eid = (int)(t >> 6);
  if (eid >= E_EDGES + nloops) return;
  int s, d;
  if (eid < E_EDGES) {
    s = newid[src[eid]]; d = newid[dst[eid]];
    if (s < 0 || d < 0) return;
  } else { s = d = eid - E_EDGES; }
  float v = xl[(size_t)s * HIDD + lane] + xr[(size_t)d * HIDD + lane];
  v = v > 0.f ? v : 0.2f * v;
  v *= att[lane];
#pragma unroll
  for (int off = 32; off > 0; off >>= 1) v += __shfl_xor(v, off);
  if (lane == 0) eo[eid] = v;
}

__global__ __launch_bounds__(256) void seg_softmax1(const int* __restrict__ rowptr,
                                                    const int* __restrict__ csr_eid,
                                                    float* __restrict__ e, int n) {
  int d = blockIdx.x * blockDim.x + threadIdx.x;
  if (d >= n) return;
  int b0 = rowptr[d], b1 = rowptr[d + 1];
  float m = -INFINITY;
  for (int j = b0; j < b1; j++) m = fmaxf(m, e[csr_eid[j]]);
  float den = 0.f;
  for (int j = b0; j < b1; j++) den += expf(e[csr_eid[j]] - m);
  float inv = 1.f / den;
  for (int j = b0; j < b1; j++) { int p = csr_eid[j]; e[p] = expf(e[p] - m) * inv; }
}

__global__ __launch_bounds__(256) void gat2_agg_csr(const int* __restrict__ rowptr,
                                                    const int* __restrict__ csr_eid,
                                                    const int* __restrict__ src,
                                                    const int* __restrict__ newid,
                                                    const float* __restrict__ alpha,
                                                    const float* __restrict__ xl,
                                                    const float* __restrict__ bias,
                                                    float* __restrict__ out, int n) {
  int lane = threadIdx.x & 63;
  long long t = (long long)blockIdx.x * blockDim.x + threadIdx.x;
  int d = (int)(t >> 6);
  if (d >= n) return;
  int b0 = rowptr[d], b1 = rowptr[d + 1];
  float acc = 0.f;
  for (int j = b0; j < b1; j++) {
    int eid = csr_eid[j];
    int s = (eid < E_EDGES) ? newid[src[eid]] : eid - E_EDGES;
    acc += alpha[eid] * xl[(size_t)s * HIDD + lane];
  }
  float v = acc + bias[lane];
  out[(size_t)d * HIDD + lane] = v > 0.f ? v : 0.f;
}

__global__ void col_max_mean(const float* __restrict__ X, int rows, int cols,
                             float* __restrict__ omax, float* __restrict__ omean) {
  int c = blockIdx.x;
  int tid = threadIdx.x;
  float mx = -INFINITY, sm = 0.f;
  for (int r = tid; r < rows; r += blockDim.x) {
    float v = X[(size_t)r * cols + c];
    mx = fmaxf(mx, v);
    sm += v;
  }
  __shared__ float smx[256], ssm[256];
  smx[tid] = mx; ssm[tid] = sm;
  __syncthreads();
  for (int s = 128; s > 0; s >>= 1) {
    if (tid < s) { smx[tid] = fmaxf(smx[tid], smx[tid + s]); ssm[tid] += ssm[tid + s]; }
    __syncthreads();
  }
  if (tid == 0) { omax[c] = smx[0]; omean[c] = ssm[0] / rows; }
}

__global__ __launch_bounds__(512) void mlp_head(const float* __restrict__ x1max,
                                                const float* __restrict__ x1mean,
                                                const float* __restrict__ g2max,
                                                const float* __restrict__ g2mean,
                                                const float* __restrict__ w1, const float* __restrict__ b1,
                                                const float* __restrict__ w2, const float* __restrict__ b2,
                                                const float* __restrict__ w3, const float* __restrict__ b3,
                                                const float* __restrict__ w4, const float* __restrict__ b4,
                                                float* __restrict__ out) {
  __shared__ float z[1024], z1[512], z2[256], z3[128], lg[2];
  int tid = threadIdx.x;
  for (int i = tid; i < 1024; i += 512) {
    float xv = (i < 512) ? x1max[i] : x1mean[i - 512];
    float gv = (i < 512) ? g2max[i & 63] : g2mean[i & 63];
    z[i] = xv + gv;
  }
  __syncthreads();
  {
    float acc = b1[tid];
    for (int k = 0; k < 1024; k++) acc += z[k] * w1[k * 512 + tid];
    z1[tid] = acc > 0.f ? acc : 0.f;
  }
  __syncthreads();
  if (tid < 256) {
    float acc = b2[tid];
    for (int k = 0; k < 512; k++) acc += z1[k] * w2[k * 256 + tid];
    z2[tid] = acc > 0.f ? acc : 0.f;
  }
  __syncthreads();
  if (tid < 128) {
    float acc = b3[tid];
    for (int k = 0; k < 256; k++) acc += z2[k] * w3[k * 128 + tid];
    z3[tid] = acc > 0.f ? acc : 0.f;
  }
  __syncthreads();
  if (tid < 2) {
    float acc = b4[tid];
    for (int k = 0; k < 128; k++) acc += z3[k] * w4[k * 2 + tid];
    lg[tid] = acc;
  }
  __syncthreads();
  if (tid == 0) {
    float m = fmaxf(lg[0], lg[1]);
    float e0 = expf(lg[0] - m), e1 = expf(lg[1] - m);
    float s = e0 + e1;
    out[0] = lg[0]; out[1] = lg[1];
    out[2] = e0 / s; out[3] = e1 / s;
  }
}

extern "C" void kernel_launch(void* const* d_in, const int* in_sizes, int n_in,
                              void* d_out, int out_size, void* d_ws, size_t ws_size,
                              hipStream_t stream) {
  const float* x       = (const float*)d_in[0];
  const int*   ei      = (const int*)d_in[1];
  const float* g1_wl   = (const float*)d_in[2];
  const float* g1_wr   = (const float*)d_in[3];
  const float* g1_att  = (const float*)d_in[4];
  const float* g1_b    = (const float*)d_in[5];
  const float* p1_w    = (const float*)d_in[6];
  const float* p1_asrc = (const float*)d_in[7];
  const float* p1_adst = (const float*)d_in[8];
  const float* p1_b    = (const float*)d_in[9];
  const float* p1_sel  = (const float*)d_in[10];
  const float* g2_wl   = (const float*)d_in[11];
  const float* g2_wr   = (const float*)d_in[12];
  const float* g2_att  = (const float*)d_in[13];
  const float* g2_b    = (const float*)d_in[14];
  const float* p2_w    = (const float*)d_in[15];
  const float* p2_asrc = (const float*)d_in[16];
  const float* p2_adst = (const float*)d_in[17];
  const float* p2_b    = (const float*)d_in[18];
  const float* p2_sel  = (const float*)d_in[19];
  const float* l1_w    = (const float*)d_in[20];
  const float* l1_b    = (const float*)d_in[21];
  const float* l2_w    = (const float*)d_in[22];
  const float* l2_b    = (const float*)d_in[23];
  const float* l3_w    = (const float*)d_in[24];
  const float* l3_b    = (const float*)d_in[25];
  const float* l4_w    = (const float*)d_in[26];
  const float* l4_b    = (const float*)d_in[27];

  const int* src = ei;
  const int* dst = ei + E_EDGES;

  // ---- arena: 33,440,000 f32 = 133.8 MB (fits the 135.2 MB bound verified in R0) ----
  if (ws_size < (size_t)33440000 * 4) return;
  float* ws  = (float*)d_ws;
  float* xl1 = ws;                 // [0, 10.24M)  stage-1 Wl·x ; later hp1 (7.68M)
  float* xr1 = ws + 10240000;      // [10.24M, 20.48M) stage-1 Wr·x ; later arena2
  float* h1  = ws + 20480000;      // [20.48M, 30.72M)
  float* e1  = ws + 30720000;      // [30.72M, 33.44M) raw scores -> alpha (E1*8)

  // arena2 lives in xr1's region; everything here is written AFTER gat1_edge_scores
  float* a2 = xr1;
  int*   csr_eid1 = (int*)a2;              // 340000
  int*   rowptr1  = (int*)(a2 + 340000);   // 20001
  int*   deg1     = (int*)(a2 + 360064);   // 20000 (deg -> cursor)
  int*   rank1    = (int*)(a2 + 380064);   // 20000
  int*   newid1   = (int*)(a2 + 400064);   // 20000
  float* xls1     = a2 + 420064;           // 20000
  float* scr1     = a2 + 440064;           // 20000
  float* x1max    = a2 + 460064;           // 512
  float* x1mean   = a2 + 460576;           // 512
  float* g2max    = a2 + 461088;           // 64
  float* g2mean   = a2 + 461152;           // 64
  float* xl2      = a2 + 461248;           // 960000
  float* xr2      = a2 + 1421248;          // 960000
  float* h2       = a2 + 2381248;          // 960000
  float* e2       = a2 + 3341248;          // 335000
  int*   csr_eid2 = (int*)(a2 + 3676248);  // 335000
  int*   rowptr2  = (int*)(a2 + 4011248);  // 15001
  int*   deg2     = (int*)(a2 + 4026304);  // 15000
  int*   rank2    = (int*)(a2 + 4041304);  // 15000
  int*   newid2   = (int*)(a2 + 4056304);  // 15000
  float* xls2     = a2 + 4071304;          // 15000
  float* scr2     = a2 + 4086304;          // 15000
  float* hp2      = a2 + 4101304;          // 720000 (ends 4,821,304 < 10.24M)
  float* hp1      = xl1;

  dim3 b256(256);
  const int E1 = E_EDGES + N_NODES;   // 340000
  const int E2 = E_EDGES + K1N;       // 335000

  // ---- Stage 1 GEMMs + raw edge scores ----
  gemm_f32<<<dim3(8, 313), b256, 0, stream>>>(x, g1_wl, xl1, N_NODES, HHD, DIN);
  gemm_f32<<<dim3(8, 313), b256, 0, stream>>>(x, g1_wr, xr1, N_NODES, HHD, DIN);
  gat1_edge_scores<<<cdiv((long long)E1 * 64, 256), b256, 0, stream>>>(src, dst, xl1, xr1, g1_att, e1);

  // ---- CSR1 (xr1 now free) ----
  fill_i32<<<cdiv(N_NODES, 256), b256, 0, stream>>>(deg1, 0, N_NODES);
  deg_count<<<cdiv(E1, 256), b256, 0, stream>>>(src, dst, nullptr, deg1, N_NODES);
  scan_excl<<<1, 1024, 0, stream>>>(deg1, rowptr1, deg1, N_NODES);
  csr_scatter<<<cdiv(E1, 256), b256, 0, stream>>>(src, dst, nullptr, deg1, csr_eid1, N_NODES);

  // ---- softmax + aggregate (bias+relu fused) ----
  seg_softmax8<<<cdiv((long long)N_NODES * 8, 256), b256, 0, stream>>>(rowptr1, csr_eid1, e1, N_NODES);
  gat1_agg_csr<<<cdiv((long long)N_NODES * 64, 256), b256, 0, stream>>>(rowptr1, csr_eid1, src, e1, xl1, g1_b, h1);

  // ---- Pool 1 ----
  proj_dot<<<cdiv((long long)N_NODES * 64, 256), b256, 0, stream>>>(h1, p1_w, xls1, N_NODES, HHD);
  pool_score<<<cdiv(N_NODES, 256), b256, 0, stream>>>(rowptr1, csr_eid1, src, nullptr, xls1,
                                                      p1_asrc, p1_adst, p1_b, p1_sel, scr1, N_NODES);
  fill_i32<<<cdiv(N_NODES, 256), b256, 0, stream>>>(rank1, 0, N_NODES);
  topk_count<<<dim3(cdiv(N_NODES, 256), cdiv(N_NODES, TK_CHUNK)), b256, 0, stream>>>(scr1, rank1, N_NODES);
  topk_assign<<<cdiv(N_NODES, 256), b256, 0, stream>>>(rank1, newid1, N_NODES, K1N);
  pool_features<<<cdiv((long long)N_NODES * HHD, 256), b256, 0, stream>>>(h1, scr1, newid1, hp1, N_NODES, HHD);
  col_max_mean<<<HHD, b256, 0, stream>>>(hp1, K1N, HHD, x1max, x1mean);

  // ---- Stage 2 GEMMs + raw edge scores ----
  gemm_f32<<<dim3(1, cdiv(K1N, 64)), b256, 0, stream>>>(hp1, g2_wl, xl2, K1N, HIDD, HHD);
  gemm_f32<<<dim3(1, cdiv(K1N, 64)), b256, 0, stream>>>(hp1, g2_wr, xr2, K1N, HIDD, HHD);
  gat2_edge_scores<<<cdiv((long long)E2 * 64, 256), b256, 0, stream>>>(src, dst, newid1, xl2, xr2, g2_att, e2, K1N);

  // ---- CSR2 ----
  fill_i32<<<cdiv(K1N, 256), b256, 0, stream>>>(deg2, 0, K1N);
  deg_count<<<cdiv(E2, 256), b256, 0, stream>>>(src, dst, newid1, deg2, K1N);
  scan_excl<<<1, 1024, 0, stream>>>(deg2, rowptr2, deg2, K1N);
  csr_scatter<<<cdiv(E2, 256), b256, 0, stream>>>(src, dst, newid1, deg2, csr_eid2, K1N);

  seg_softmax1<<<cdiv(K1N, 256), b256, 0, stream>>>(rowptr2, csr_eid2, e2, K1N);
  gat2_agg_csr<<<cdiv((long long)K1N * 64, 256), b256, 0, stream>>>(rowptr2, csr_eid2, src, newid1, e2, xl2, g2_b, h2, K1N);

  // ---- Pool 2 ----
  proj_dot<<<cdiv((long long)K1N * 64, 256), b256, 0, stream>>>(h2, p2_w, xls2, K1N, HIDD);
  pool_score<<<cdiv(K1N, 256), b256, 0, stream>>>(rowptr2, csr_eid2, src, newid1, xls2,
                                                  p2_asrc, p2_adst, p2_b, p2_sel, scr2, K1N);
  fill_i32<<<cdiv(K1N, 256), b256, 0, stream>>>(rank2, 0, K1N);
  topk_count<<<dim3(cdiv(K1N, 256), cdiv(K1N, TK_CHUNK)), b256, 0, stream>>>(scr2, rank2, K1N);
  topk_assign<<<cdiv(K1N, 256), b256, 0, stream>>>(rank2, newid2, K1N, K2N);
  pool_features<<<cdiv((long long)K1N * HIDD, 256), b256, 0, stream>>>(h2, scr2, newid2, hp2, K1N, HIDD);
  col_max_mean<<<HIDD, b256, 0, stream>>>(hp2, K2N, HIDD, g2max, g2mean);

  // ---- Readout + MLP head ----
  mlp_head<<<1, 512, 0, stream>>>(x1max, x1mean, g2max, g2mean,
                                  l1_w, l1_b, l2_w, l2_b, l3_w, l3_b, l4_w, l4_b,
                                  (float*)d_out);
}

// Round 3
// 982.150 us; speedup vs baseline: 2.7135x; 1.2793x over previous
//
#include <hip/hip_runtime.h>
#include <math.h>

#define N_NODES 20000
#define E_EDGES 320000
#define DIN     256
#define HHD     512
#define HIDD    64
#define NHEADS  8
#define K1N     15000
#define K2N     11250

static inline int cdiv(long long a, long long b) { return (int)((a + b - 1) / b); }

__device__ __forceinline__ void atomicMaxF(float* addr, float val) {
  int* ai = (int*)addr;
  int old = __float_as_int(*addr);
  while (__int_as_float(old) < val) {
    int assumed = old;
    old = atomicCAS(ai, assumed, __float_as_int(val));
    if (old == assumed) break;
  }
}

__global__ void fill_i32(int* p, int v, int n) {
  int i = blockIdx.x * blockDim.x + threadIdx.x;
  if (i < n) p[i] = v;
}

__global__ void pool_init(float* x1max, float* x1sum, float* g2max, float* g2sum) {
  int i = blockIdx.x * blockDim.x + threadIdx.x;
  if (i < 512) x1max[i] = -INFINITY;
  else if (i < 1024) x1sum[i - 512] = 0.f;
  else if (i < 1088) g2max[i - 1024] = -INFINITY;
  else if (i < 1152) g2sum[i - 1088] = 0.f;
}

// C[M,Nc] = A[M,K] @ W[K,Nc]; requires Nc % 64 == 0, K % 16 == 0; M bounds-checked.
__global__ __launch_bounds__(256) void gemm_f32(const float* __restrict__ A,
                                                const float* __restrict__ W,
                                                float* __restrict__ C,
                                                int M, int Nc, int K) {
  __shared__ float As[16][65];
  __shared__ float Ws[16][64];
  int tid = threadIdx.x;
  int tr = tid >> 4, tc = tid & 15;
  int brow = blockIdx.y * 64, bcol = blockIdx.x * 64;
  float acc[4][4] = {{0.f}};
  for (int k0 = 0; k0 < K; k0 += 16) {
    for (int i = tid; i < 64 * 16; i += 256) {
      int r = i >> 4, kk = i & 15;
      int gr = brow + r;
      As[kk][r] = (gr < M) ? A[(size_t)gr * K + k0 + kk] : 0.f;
    }
    for (int i = tid; i < 16 * 64; i += 256) {
      int kk = i >> 6, c = i & 63;
      Ws[kk][c] = W[(size_t)(k0 + kk) * Nc + bcol + c];
    }
    __syncthreads();
#pragma unroll
    for (int kk = 0; kk < 16; kk++) {
      float a[4], w[4];
#pragma unroll
      for (int u = 0; u < 4; u++) a[u] = As[kk][tr * 4 + u];
#pragma unroll
      for (int u = 0; u < 4; u++) w[u] = Ws[kk][tc * 4 + u];
#pragma unroll
      for (int u = 0; u < 4; u++)
#pragma unroll
        for (int v = 0; v < 4; v++) acc[u][v] += a[u] * w[v];
    }
    __syncthreads();
  }
  for (int u = 0; u < 4; u++) {
    int gr = brow + tr * 4 + u;
    if (gr < M)
      for (int v = 0; v < 4; v++)
        C[(size_t)gr * Nc + bcol + tc * 4 + v] = acc[u][v];
  }
}

// ---------------- CSR construction ----------------
__global__ void deg_count(const int* __restrict__ src, const int* __restrict__ dst,
                          const int* __restrict__ newid, int* __restrict__ deg,
                          int nloops) {
  int i = blockIdx.x * blockDim.x + threadIdx.x;
  if (i >= E_EDGES + nloops) return;
  int d;
  if (i < E_EDGES) {
    if (newid) {
      int s = newid[src[i]]; d = newid[dst[i]];
      if (s < 0 || d < 0) return;
    } else d = dst[i];
  } else d = i - E_EDGES;
  atomicAdd(&deg[d], 1);
}

__global__ __launch_bounds__(1024) void scan_excl(const int* deg, int* rowptr,
                                                  int* cursor, int n) {
  __shared__ int buf[1024];
  __shared__ int carry;
  int tid = threadIdx.x;
  if (tid == 0) { carry = 0; rowptr[0] = 0; }
  __syncthreads();
  for (int base = 0; base < n; base += 1024) {
    int v = (base + tid < n) ? deg[base + tid] : 0;
    buf[tid] = v;
    __syncthreads();
    for (int off = 1; off < 1024; off <<= 1) {
      int t = (tid >= off) ? buf[tid - off] : 0;
      __syncthreads();
      buf[tid] += t;
      __syncthreads();
    }
    int incl = buf[tid] + carry;
    if (base + tid < n) { rowptr[base + tid + 1] = incl; cursor[base + tid] = incl - v; }
    __syncthreads();
    if (tid == 1023) carry = incl;
    __syncthreads();
  }
}

__global__ void csr_scatter(const int* __restrict__ src, const int* __restrict__ dst,
                            const int* __restrict__ newid, int* __restrict__ cursor,
                            int* __restrict__ csr_eid, int nloops) {
  int i = blockIdx.x * blockDim.x + threadIdx.x;
  if (i >= E_EDGES + nloops) return;
  int d;
  if (i < E_EDGES) {
    if (newid) {
      int s = newid[src[i]]; d = newid[dst[i]];
      if (s < 0 || d < 0) return;
    } else d = dst[i];
  } else d = i - E_EDGES;
  int pos = atomicAdd(&cursor[d], 1);
  csr_eid[pos] = i;
}

// ---------------- Stage 1 fused: GATv2 score + online softmax + aggregate + proj ----------------
// one wave per dst node; lane holds 8 consecutive cols (head = lane>>3)
__global__ __launch_bounds__(256) void gat1_fused(const int* __restrict__ rowptr,
                                                  const int* __restrict__ csr_eid,
                                                  const int* __restrict__ src,
                                                  const float* __restrict__ xl,
                                                  const float* __restrict__ xr,
                                                  const float* __restrict__ att,
                                                  const float* __restrict__ bias,
                                                  const float* __restrict__ pw,
                                                  float* __restrict__ out,
                                                  float* __restrict__ xls) {
  int lane = threadIdx.x & 63;
  long long t = (long long)blockIdx.x * blockDim.x + threadIdx.x;
  int d = (int)(t >> 6);
  if (d >= N_NODES) return;
  int base = lane * 8;
  float4 a0 = *(const float4*)(att + base);
  float4 a1 = *(const float4*)(att + base + 4);
  const float* xrp = xr + (size_t)d * HHD + base;
  float4 r0 = *(const float4*)(xrp);
  float4 r1 = *(const float4*)(xrp + 4);
  float m = -INFINITY, den = 0.f;
  float acc[8] = {0.f, 0.f, 0.f, 0.f, 0.f, 0.f, 0.f, 0.f};
  int b0 = rowptr[d], b1 = rowptr[d + 1];
  for (int j = b0; j < b1; j++) {
    int eid = csr_eid[j];
    int s = (eid < E_EDGES) ? src[eid] : eid - E_EDGES;
    const float* xlp = xl + (size_t)s * HHD + base;
    float4 v0 = *(const float4*)(xlp);
    float4 v1 = *(const float4*)(xlp + 4);
    float p, tv;
    tv = v0.x + r0.x; tv = tv > 0.f ? tv : 0.2f * tv; p  = tv * a0.x;
    tv = v0.y + r0.y; tv = tv > 0.f ? tv : 0.2f * tv; p += tv * a0.y;
    tv = v0.z + r0.z; tv = tv > 0.f ? tv : 0.2f * tv; p += tv * a0.z;
    tv = v0.w + r0.w; tv = tv > 0.f ? tv : 0.2f * tv; p += tv * a0.w;
    tv = v1.x + r1.x; tv = tv > 0.f ? tv : 0.2f * tv; p += tv * a1.x;
    tv = v1.y + r1.y; tv = tv > 0.f ? tv : 0.2f * tv; p += tv * a1.y;
    tv = v1.z + r1.z; tv = tv > 0.f ? tv : 0.2f * tv; p += tv * a1.z;
    tv = v1.w + r1.w; tv = tv > 0.f ? tv : 0.2f * tv; p += tv * a1.w;
    p += __shfl_xor(p, 1); p += __shfl_xor(p, 2); p += __shfl_xor(p, 4);
    // p == head score e, identical across the 8-lane head group
    float nm = fmaxf(m, p);
    float w  = __expf(p - nm);
    float sc = __expf(m - nm);
    den = den * sc + w;
    acc[0] = acc[0] * sc + w * v0.x;
    acc[1] = acc[1] * sc + w * v0.y;
    acc[2] = acc[2] * sc + w * v0.z;
    acc[3] = acc[3] * sc + w * v0.w;
    acc[4] = acc[4] * sc + w * v1.x;
    acc[5] = acc[5] * sc + w * v1.y;
    acc[6] = acc[6] * sc + w * v1.z;
    acc[7] = acc[7] * sc + w * v1.w;
    m = nm;
  }
  float inv = 1.f / den;
  float4 b0v = *(const float4*)(bias + base);
  float4 b1v = *(const float4*)(bias + base + 4);
  float o[8];
  o[0] = acc[0] * inv + b0v.x; o[1] = acc[1] * inv + b0v.y;
  o[2] = acc[2] * inv + b0v.z; o[3] = acc[3] * inv + b0v.w;
  o[4] = acc[4] * inv + b1v.x; o[5] = acc[5] * inv + b1v.y;
  o[6] = acc[6] * inv + b1v.z; o[7] = acc[7] * inv + b1v.w;
#pragma unroll
  for (int k = 0; k < 8; k++) o[k] = o[k] > 0.f ? o[k] : 0.f;
  float* op = out + (size_t)d * HHD + base;
  *(float4*)(op)     = make_float4(o[0], o[1], o[2], o[3]);
  *(float4*)(op + 4) = make_float4(o[4], o[5], o[6], o[7]);
  // fused projection: xls[d] = dot(out_row, pw)
  float4 w0 = *(const float4*)(pw + base);
  float4 w1 = *(const float4*)(pw + base + 4);
  float sdot = o[0]*w0.x + o[1]*w0.y + o[2]*w0.z + o[3]*w0.w
             + o[4]*w1.x + o[5]*w1.y + o[6]*w1.z + o[7]*w1.w;
#pragma unroll
  for (int off = 32; off > 0; off >>= 1) sdot += __shfl_xor(sdot, off);
  if (lane == 0) xls[d] = sdot;
}

// ---------------- Stage 2 fused: heads=1, dim 64, lane = col ----------------
__global__ __launch_bounds__(256) void gat2_fused(const int* __restrict__ rowptr,
                                                  const int* __restrict__ csr_eid,
                                                  const int* __restrict__ src,
                                                  const int* __restrict__ newid,
                                                  const float* __restrict__ xl,
                                                  const float* __restrict__ xr,
                                                  const float* __restrict__ att,
                                                  const float* __restrict__ bias,
                                                  const float* __restrict__ pw,
                                                  float* __restrict__ out,
                                                  float* __restrict__ xls, int n) {
  int lane = threadIdx.x & 63;
  long long t = (long long)blockIdx.x * blockDim.x + threadIdx.x;
  int d = (int)(t >> 6);
  if (d >= n) return;
  float av = att[lane];
  float rr = xr[(size_t)d * HIDD + lane];
  float m = -INFINITY, den = 0.f, acc = 0.f;
  int b0 = rowptr[d], b1 = rowptr[d + 1];
  for (int j = b0; j < b1; j++) {
    int eid = csr_eid[j];
    int s = (eid < E_EDGES) ? newid[src[eid]] : eid - E_EDGES;
    float v = xl[(size_t)s * HIDD + lane];
    float tv = v + rr; tv = tv > 0.f ? tv : 0.2f * tv;
    float p = tv * av;
#pragma unroll
    for (int off = 32; off > 0; off >>= 1) p += __shfl_xor(p, off);
    float nm = fmaxf(m, p);
    float w  = __expf(p - nm);
    float sc = __expf(m - nm);
    den = den * sc + w;
    acc = acc * sc + w * v;
    m = nm;
  }
  float o = acc / den + bias[lane];
  o = o > 0.f ? o : 0.f;
  out[(size_t)d * HIDD + lane] = o;
  float sdot = o * pw[lane];
#pragma unroll
  for (int off = 32; off > 0; off >>= 1) sdot += __shfl_xor(sdot, off);
  if (lane == 0) xls[d] = sdot;
}

// ---------------- pool scoring over CSR (scalar GATConv -> tanh) ----------------
__global__ __launch_bounds__(256) void pool_score(const int* __restrict__ rowptr,
                                                  const int* __restrict__ csr_eid,
                                                  const int* __restrict__ src,
                                                  const int* __restrict__ newid_map,
                                                  const float* __restrict__ xls,
                                                  const float* __restrict__ asrc,
                                                  const float* __restrict__ adst,
                                                  const float* __restrict__ bias,
                                                  const float* __restrict__ sel,
                                                  float* __restrict__ score, int n) {
  int d = blockIdx.x * blockDim.x + threadIdx.x;
  if (d >= n) return;
  float as = asrc[0], ad = adst[0];
  float ar = xls[d] * ad;
  int b0 = rowptr[d], b1 = rowptr[d + 1];
  float m = -INFINITY;
  for (int j = b0; j < b1; j++) {
    int eid = csr_eid[j];
    int s = (eid < E_EDGES) ? (newid_map ? newid_map[src[eid]] : src[eid]) : eid - E_EDGES;
    float e = xls[s] * as + ar;
    e = e > 0.f ? e : 0.2f * e;
    m = fmaxf(m, e);
  }
  float den = 0.f, num = 0.f;
  for (int j = b0; j < b1; j++) {
    int eid = csr_eid[j];
    int s = (eid < E_EDGES) ? (newid_map ? newid_map[src[eid]] : src[eid]) : eid - E_EDGES;
    float xs = xls[s];
    float e = xs * as + ar;
    e = e > 0.f ? e : 0.2f * e;
    float ex = __expf(e - m);
    den += ex; num += ex * xs;
  }
  float attn = num / den + bias[0];
  float sv = sel[0];
  score[d] = tanhf(attn * sv / fabsf(sv));
}

// ---------------- top-k via 2D-grid rank counting ----------------
#define TK_CHUNK 512
__global__ __launch_bounds__(256) void topk_count(const float* __restrict__ score,
                                                  int* __restrict__ rank, int n) {
  __shared__ float sc[TK_CHUNK];
  int i = blockIdx.x * 256 + threadIdx.x;
  int base = blockIdx.y * TK_CHUNK;
  int cnt = min(TK_CHUNK, n - base);
  for (int j = threadIdx.x; j < cnt; j += 256) sc[j] = score[base + j];
  __syncthreads();
  if (i >= n) return;
  float si = score[i];
  int r = 0;
  for (int j = 0; j < cnt; j++) {
    float sj = sc[j];
    r += (sj > si) || ((sj == si) && ((base + j) < i));
  }
  if (r) atomicAdd(&rank[i], r);
}

__global__ void topk_assign(const int* __restrict__ rank, int* __restrict__ newid,
                            int n, int k) {
  int i = blockIdx.x * blockDim.x + threadIdx.x;
  if (i < n) newid[i] = (rank[i] < k) ? rank[i] : -1;
}

__global__ void pool_features(const float* __restrict__ h, const float* __restrict__ score,
                              const int* __restrict__ newid, float* __restrict__ hp,
                              int n, int F) {
  long long i = (long long)blockIdx.x * blockDim.x + threadIdx.x;
  if (i >= (long long)n * F) return;
  int node = (int)(i / F), c = (int)(i % F);
  int nid = newid[node];
  if (nid < 0) return;
  hp[(size_t)nid * F + c] = h[i] * score[node];
}

// coalesced column max/sum with per-block register reduction + atomic merge
__global__ __launch_bounds__(256) void col_pool(const float* __restrict__ X, int rows, int C,
                                                float* __restrict__ omax, float* __restrict__ osum) {
  int tid = threadIdx.x;
  float mx[2] = {-INFINITY, -INFINITY};
  float sm[2] = {0.f, 0.f};
  int nseg = (C + 255) / 256;   // 1 or 2
  int rpb = (rows + gridDim.x - 1) / gridDim.x;
  int rbeg = blockIdx.x * rpb;
  int rend = min(rows, rbeg + rpb);
  for (int r = rbeg; r < rend; r++) {
    const float* row = X + (size_t)r * C;
    for (int sg = 0; sg < nseg; sg++) {
      int c = sg * 256 + tid;
      if (c < C) {
        float v = row[c];
        mx[sg] = fmaxf(mx[sg], v);
        sm[sg] += v;
      }
    }
  }
  if (rbeg < rend) {
    for (int sg = 0; sg < nseg; sg++) {
      int c = sg * 256 + tid;
      if (c < C) { atomicMaxF(&omax[c], mx[sg]); atomicAdd(&osum[c], sm[sg]); }
    }
  }
}

__global__ __launch_bounds__(512) void mlp_head(const float* __restrict__ x1max,
                                                const float* __restrict__ x1sum,
                                                const float* __restrict__ g2max,
                                                const float* __restrict__ g2sum,
                                                const float* __restrict__ w1, const float* __restrict__ b1,
                                                const float* __restrict__ w2, const float* __restrict__ b2,
                                                const float* __restrict__ w3, const float* __restrict__ b3,
                                                const float* __restrict__ w4, const float* __restrict__ b4,
                                                float* __restrict__ out) {
  __shared__ float z[1024], z1[512], z2[256], z3[128], lg[2];
  int tid = threadIdx.x;
  const float inv1 = 1.f / K1N, inv2 = 1.f / K2N;
  for (int i = tid; i < 1024; i += 512) {
    float xv = (i < 512) ? x1max[i] : x1sum[i - 512] * inv1;
    float gv = (i < 512) ? g2max[i & 63] : g2sum[i & 63] * inv2;
    z[i] = xv + gv;
  }
  __syncthreads();
  {
    float acc = b1[tid];
    for (int k = 0; k < 1024; k++) acc += z[k] * w1[k * 512 + tid];
    z1[tid] = acc > 0.f ? acc : 0.f;
  }
  __syncthreads();
  if (tid < 256) {
    float acc = b2[tid];
    for (int k = 0; k < 512; k++) acc += z1[k] * w2[k * 256 + tid];
    z2[tid] = acc > 0.f ? acc : 0.f;
  }
  __syncthreads();
  if (tid < 128) {
    float acc = b3[tid];
    for (int k = 0; k < 256; k++) acc += z2[k] * w3[k * 128 + tid];
    z3[tid] = acc > 0.f ? acc : 0.f;
  }
  __syncthreads();
  if (tid < 2) {
    float acc = b4[tid];
    for (int k = 0; k < 128; k++) acc += z3[k] * w4[k * 2 + tid];
    lg[tid] = acc;
  }
  __syncthreads();
  if (tid == 0) {
    float m = fmaxf(lg[0], lg[1]);
    float e0 = expf(lg[0] - m), e1 = expf(lg[1] - m);
    float s = e0 + e1;
    out[0] = lg[0]; out[1] = lg[1];
    out[2] = e0 / s; out[3] = e1 / s;
  }
}

extern "C" void kernel_launch(void* const* d_in, const int* in_sizes, int n_in,
                              void* d_out, int out_size, void* d_ws, size_t ws_size,
                              hipStream_t stream) {
  const float* x       = (const float*)d_in[0];
  const int*   ei      = (const int*)d_in[1];
  const float* g1_wl   = (const float*)d_in[2];
  const float* g1_wr   = (const float*)d_in[3];
  const float* g1_att  = (const float*)d_in[4];
  const float* g1_b    = (const float*)d_in[5];
  const float* p1_w    = (const float*)d_in[6];
  const float* p1_asrc = (const float*)d_in[7];
  const float* p1_adst = (const float*)d_in[8];
  const float* p1_b    = (const float*)d_in[9];
  const float* p1_sel  = (const float*)d_in[10];
  const float* g2_wl   = (const float*)d_in[11];
  const float* g2_wr   = (const float*)d_in[12];
  const float* g2_att  = (const float*)d_in[13];
  const float* g2_b    = (const float*)d_in[14];
  const float* p2_w    = (const float*)d_in[15];
  const float* p2_asrc = (const float*)d_in[16];
  const float* p2_adst = (const float*)d_in[17];
  const float* p2_b    = (const float*)d_in[18];
  const float* p2_sel  = (const float*)d_in[19];
  const float* l1_w    = (const float*)d_in[20];
  const float* l1_b    = (const float*)d_in[21];
  const float* l2_w    = (const float*)d_in[22];
  const float* l2_b    = (const float*)d_in[23];
  const float* l3_w    = (const float*)d_in[24];
  const float* l3_b    = (const float*)d_in[25];
  const float* l4_w    = (const float*)d_in[26];
  const float* l4_b    = (const float*)d_in[27];

  const int* src = ei;
  const int* dst = ei + E_EDGES;

  if (ws_size < (size_t)33440000 * 4) return;
  float* ws  = (float*)d_ws;
  float* xl1 = ws;                 // 10.24M; later hp1
  float* xr1 = ws + 10240000;      // 10.24M; later arena2
  float* h1  = ws + 20480000;      // 10.24M
  float* aux = ws + 30720000;      // 2.72M persistent

  int*   csr_eid1 = (int*)aux;               // 340000
  int*   rowptr1  = (int*)(aux + 340000);    // 20001
  int*   deg1     = (int*)(aux + 360064);    // 20000 (deg -> cursor)
  int*   rank1    = (int*)(aux + 380064);    // 20000
  int*   newid1   = (int*)(aux + 400064);    // 20000
  float* xls1     = aux + 420064;            // 20000
  float* scr1     = aux + 440064;            // 20000
  float* x1max    = aux + 460064;            // 512
  float* x1sum    = aux + 460576;            // 512
  float* g2max    = aux + 461088;            // 64
  float* g2sum    = aux + 461152;            // 64

  float* a2 = xr1;                           // stage-2 arena (xr1 dead after gat1_fused)
  float* xl2      = a2;                      // 960000
  float* xr2      = a2 + 960000;             // 960000
  float* h2       = a2 + 1920000;            // 960000
  int*   csr_eid2 = (int*)(a2 + 2880000);    // 335000
  int*   rowptr2  = (int*)(a2 + 3215000);    // 15001
  int*   deg2     = (int*)(a2 + 3230016);    // 15000
  int*   rank2    = (int*)(a2 + 3245016);    // 15000
  int*   newid2   = (int*)(a2 + 3260016);    // 15000
  float* xls2     = a2 + 3275016;            // 15000
  float* scr2     = a2 + 3290016;            // 15000
  float* hp2      = a2 + 3305016;            // 720000 (ends 4,025,016 < 10.24M)
  float* hp1      = xl1;

  dim3 b256(256);
  const int E1 = E_EDGES + N_NODES;   // 340000
  const int E2 = E_EDGES + K1N;       // 335000

  // ---- init + CSR1 (feature-independent) ----
  pool_init<<<5, b256, 0, stream>>>(x1max, x1sum, g2max, g2sum);
  fill_i32<<<cdiv(N_NODES, 256), b256, 0, stream>>>(deg1, 0, N_NODES);
  deg_count<<<cdiv(E1, 256), b256, 0, stream>>>(src, dst, nullptr, deg1, N_NODES);
  scan_excl<<<1, 1024, 0, stream>>>(deg1, rowptr1, deg1, N_NODES);
  csr_scatter<<<cdiv(E1, 256), b256, 0, stream>>>(src, dst, nullptr, deg1, csr_eid1, N_NODES);

  // ---- Stage 1 GEMMs + fused GAT ----
  gemm_f32<<<dim3(8, 313), b256, 0, stream>>>(x, g1_wl, xl1, N_NODES, HHD, DIN);
  gemm_f32<<<dim3(8, 313), b256, 0, stream>>>(x, g1_wr, xr1, N_NODES, HHD, DIN);
  gat1_fused<<<cdiv((long long)N_NODES * 64, 256), b256, 0, stream>>>(
      rowptr1, csr_eid1, src, xl1, xr1, g1_att, g1_b, p1_w, h1, xls1);

  // ---- Pool 1 ----
  pool_score<<<cdiv(N_NODES, 256), b256, 0, stream>>>(rowptr1, csr_eid1, src, nullptr, xls1,
                                                      p1_asrc, p1_adst, p1_b, p1_sel, scr1, N_NODES);
  fill_i32<<<cdiv(N_NODES, 256), b256, 0, stream>>>(rank1, 0, N_NODES);
  topk_count<<<dim3(cdiv(N_NODES, 256), cdiv(N_NODES, TK_CHUNK)), b256, 0, stream>>>(scr1, rank1, N_NODES);
  topk_assign<<<cdiv(N_NODES, 256), b256, 0, stream>>>(rank1, newid1, N_NODES, K1N);
  pool_features<<<cdiv((long long)N_NODES * HHD, 256), b256, 0, stream>>>(h1, scr1, newid1, hp1, N_NODES, HHD);
  col_pool<<<128, b256, 0, stream>>>(hp1, K1N, HHD, x1max, x1sum);

  // ---- CSR2 + Stage 2 GEMMs + fused GAT ----
  fill_i32<<<cdiv(K1N, 256), b256, 0, stream>>>(deg2, 0, K1N);
  deg_count<<<cdiv(E2, 256), b256, 0, stream>>>(src, dst, newid1, deg2, K1N);
  scan_excl<<<1, 1024, 0, stream>>>(deg2, rowptr2, deg2, K1N);
  csr_scatter<<<cdiv(E2, 256), b256, 0, stream>>>(src, dst, newid1, deg2, csr_eid2, K1N);

  gemm_f32<<<dim3(1, cdiv(K1N, 64)), b256, 0, stream>>>(hp1, g2_wl, xl2, K1N, HIDD, HHD);
  gemm_f32<<<dim3(1, cdiv(K1N, 64)), b256, 0, stream>>>(hp1, g2_wr, xr2, K1N, HIDD, HHD);
  gat2_fused<<<cdiv((long long)K1N * 64, 256), b256, 0, stream>>>(
      rowptr2, csr_eid2, src, newid1, xl2, xr2, g2_att, g2_b, p2_w, h2, xls2, K1N);

  // ---- Pool 2 ----
  pool_score<<<cdiv(K1N, 256), b256, 0, stream>>>(rowptr2, csr_eid2, src, newid1, xls2,
                                                  p2_asrc, p2_adst, p2_b, p2_sel, scr2, K1N);
  fill_i32<<<cdiv(K1N, 256), b256, 0, stream>>>(rank2, 0, K1N);
  topk_count<<<dim3(cdiv(K1N, 256), cdiv(K1N, TK_CHUNK)), b256, 0, stream>>>(scr2, rank2, K1N);
  topk_assign<<<cdiv(K1N, 256), b256, 0, stream>>>(rank2, newid2, K1N, K2N);
  pool_features<<<cdiv((long long)K1N * HIDD, 256), b256, 0, stream>>>(h2, scr2, newid2, hp2, K1N, HIDD);
  col_pool<<<128, b256, 0, stream>>>(hp2, K2N, HIDD, g2max, g2sum);

  // ---- Readout + MLP head ----
  mlp_head<<<1, 512, 0, stream>>>(x1max, x1sum, g2max, g2sum,
                                  l1_w, l1_b, l2_w, l2_b, l3_w, l3_b, l4_w, l4_b,
                                  (float*)d_out);
}

// Round 4
// 726.979 us; speedup vs baseline: 3.6659x; 1.3510x over previous
//
#include <hip/hip_runtime.h>
#include <math.h>

#define N_NODES 20000
#define E_EDGES 320000
#define DIN     256
#define HHD     512
#define HIDD    64
#define NHEADS  8
#define K1N     15000
#define K2N     11250

static inline int cdiv(long long a, long long b) { return (int)((a + b - 1) / b); }

__device__ __forceinline__ void atomicMaxF(float* addr, float val) {
  int* ai = (int*)addr;
  int old = __float_as_int(*addr);
  while (__int_as_float(old) < val) {
    int assumed = old;
    old = atomicCAS(ai, assumed, __float_as_int(val));
    if (old == assumed) break;
  }
}

__global__ void fill_i32(int* p, int v, int n) {
  int i = blockIdx.x * blockDim.x + threadIdx.x;
  if (i < n) p[i] = v;
}

// deg1[20000]=0, rank1[20000]=0, pools[1152]: [-inf x512, 0 x512, -inf x64, 0 x64]
__global__ void init_all(int* deg1, int* rank1, float* pools) {
  int i = blockIdx.x * blockDim.x + threadIdx.x;
  if (i < N_NODES) deg1[i] = 0;
  else if (i < 2 * N_NODES) rank1[i - N_NODES] = 0;
  else {
    int idx = i - 2 * N_NODES;
    if (idx < 1152)
      pools[idx] = (idx < 512 || (idx >= 1024 && idx < 1088)) ? -INFINITY : 0.f;
  }
}

// ---------------- dual-output GEMM with optional row-gather+scale on A ----------------
// C[gr][c] for c<Nc -> C1 from W1, else C2 from W2 (c-Nc). A row = perm?perm[gr]:gr, scaled.
template<int BM, int BN, int BK, int TM, int TN>
__global__ __launch_bounds__(256) void gemm_dual(const float* __restrict__ A,
                                                 const int* __restrict__ perm,
                                                 const float* __restrict__ scalev,
                                                 const float* __restrict__ W1,
                                                 const float* __restrict__ W2,
                                                 float* __restrict__ C1,
                                                 float* __restrict__ C2,
                                                 int M, int Nc, int K) {
  __shared__ float As[BK][BM + 4];
  __shared__ float Bs[BK][BN];
  int tid = threadIdx.x;
  constexpr int NTX = BN / TN;
  int tx = tid % NTX, ty = tid / NTX;
  int brow = blockIdx.y * BM, bcol0 = blockIdx.x * BN;
  const float* W = (bcol0 < Nc) ? W1 : W2;
  float* C = (bcol0 < Nc) ? C1 : C2;
  int bcol = (bcol0 < Nc) ? bcol0 : bcol0 - Nc;
  float acc[TM][TN] = {{0.f}};
  for (int k0 = 0; k0 < K; k0 += BK) {
    constexpr int AV = BM * BK / (4 * 256);
#pragma unroll
    for (int i = 0; i < AV; i++) {
      int idx = (tid + i * 256) * 4;
      int r = idx / BK, c = idx % BK;
      int gr = brow + r;
      float4 v = make_float4(0.f, 0.f, 0.f, 0.f);
      if (gr < M) {
        int ar = perm ? perm[gr] : gr;
        v = *(const float4*)(A + (size_t)ar * K + k0 + c);
        if (scalev) {
          float sc = scalev[ar];
          v.x *= sc; v.y *= sc; v.z *= sc; v.w *= sc;
        }
      }
      As[c][r] = v.x; As[c + 1][r] = v.y; As[c + 2][r] = v.z; As[c + 3][r] = v.w;
    }
    constexpr int BV = BK * BN / (4 * 256);
#pragma unroll
    for (int i = 0; i < BV; i++) {
      int idx = (tid + i * 256) * 4;
      int r = idx / BN, c = idx % BN;
      *(float4*)(&Bs[r][c]) = *(const float4*)(W + (size_t)(k0 + r) * Nc + bcol + c);
    }
    __syncthreads();
#pragma unroll
    for (int kk = 0; kk < BK; kk++) {
      float a[TM], b[TN];
#pragma unroll
      for (int u = 0; u < TM; u++) a[u] = As[kk][ty * TM + u];
#pragma unroll
      for (int v = 0; v < TN; v++) b[v] = Bs[kk][tx * TN + v];
#pragma unroll
      for (int u = 0; u < TM; u++)
#pragma unroll
        for (int v = 0; v < TN; v++) acc[u][v] += a[u] * b[v];
    }
    __syncthreads();
  }
#pragma unroll
  for (int u = 0; u < TM; u++) {
    int gr = brow + ty * TM + u;
    if (gr < M)
#pragma unroll
      for (int v = 0; v < TN; v += 4)
        *(float4*)(C + (size_t)gr * Nc + bcol + tx * TN + v) =
            make_float4(acc[u][v], acc[u][v + 1], acc[u][v + 2], acc[u][v + 3]);
  }
}

// ---------------- CSR construction ----------------
__global__ void deg_count(const int* __restrict__ src, const int* __restrict__ dst,
                          const int* __restrict__ newid, int* __restrict__ deg,
                          int nloops) {
  int i = blockIdx.x * blockDim.x + threadIdx.x;
  if (i >= E_EDGES + nloops) return;
  int d;
  if (i < E_EDGES) {
    if (newid) {
      int s = newid[src[i]]; d = newid[dst[i]];
      if (s < 0 || d < 0) return;
    } else d = dst[i];
  } else d = i - E_EDGES;
  atomicAdd(&deg[d], 1);
}

// shuffle-based single-block exclusive scan; cursor may alias deg.
__global__ __launch_bounds__(1024) void scan_excl(const int* deg, int* rowptr,
                                                  int* cursor, int n) {
  __shared__ int wsum[16];
  __shared__ int carry;
  int tid = threadIdx.x, lane = tid & 63, wid = tid >> 6;
  if (tid == 0) { carry = 0; rowptr[0] = 0; }
  __syncthreads();
  for (int base = 0; base < n; base += 1024) {
    int v = (base + tid < n) ? deg[base + tid] : 0;
    int s = v;
#pragma unroll
    for (int off = 1; off < 64; off <<= 1) {
      int t = __shfl_up(s, off);
      if (lane >= off) s += t;
    }
    if (lane == 63) wsum[wid] = s;
    __syncthreads();
    if (wid == 0) {
      int w = (lane < 16) ? wsum[lane] : 0;
#pragma unroll
      for (int off = 1; off < 16; off <<= 1) {
        int t = __shfl_up(w, off);
        if (lane >= off) w += t;
      }
      if (lane < 16) wsum[lane] = w;
    }
    __syncthreads();
    int incl = s + (wid > 0 ? wsum[wid - 1] : 0) + carry;
    if (base + tid < n) { rowptr[base + tid + 1] = incl; cursor[base + tid] = incl - v; }
    __syncthreads();
    if (tid == 1023) carry = incl;
    __syncthreads();
  }
}

__global__ void csr_scatter(const int* __restrict__ src, const int* __restrict__ dst,
                            const int* __restrict__ newid, int* __restrict__ cursor,
                            int* __restrict__ csr_eid, int nloops) {
  int i = blockIdx.x * blockDim.x + threadIdx.x;
  if (i >= E_EDGES + nloops) return;
  int d;
  if (i < E_EDGES) {
    if (newid) {
      int s = newid[src[i]]; d = newid[dst[i]];
      if (s < 0 || d < 0) return;
    } else d = dst[i];
  } else d = i - E_EDGES;
  int pos = atomicAdd(&cursor[d], 1);
  csr_eid[pos] = i;
}

// ---------------- Stage 1 fused: GATv2 score + online softmax + aggregate + proj ----------------
__global__ __launch_bounds__(256) void gat1_fused(const int* __restrict__ rowptr,
                                                  const int* __restrict__ csr_eid,
                                                  const int* __restrict__ src,
                                                  const float* __restrict__ xl,
                                                  const float* __restrict__ xr,
                                                  const float* __restrict__ att,
                                                  const float* __restrict__ bias,
                                                  const float* __restrict__ pw,
                                                  float* __restrict__ out,
                                                  float* __restrict__ xls) {
  int lane = threadIdx.x & 63;
  long long t = (long long)blockIdx.x * blockDim.x + threadIdx.x;
  int d = (int)(t >> 6);
  if (d >= N_NODES) return;
  int base = lane * 8;
  float4 a0 = *(const float4*)(att + base);
  float4 a1 = *(const float4*)(att + base + 4);
  const float* xrp = xr + (size_t)d * HHD + base;
  float4 r0 = *(const float4*)(xrp);
  float4 r1 = *(const float4*)(xrp + 4);
  float m = -INFINITY, den = 0.f;
  float acc[8] = {0.f, 0.f, 0.f, 0.f, 0.f, 0.f, 0.f, 0.f};
  int b0 = rowptr[d], b1 = rowptr[d + 1];
  for (int j = b0; j < b1; j++) {
    int eid = csr_eid[j];
    int s = (eid < E_EDGES) ? src[eid] : eid - E_EDGES;
    const float* xlp = xl + (size_t)s * HHD + base;
    float4 v0 = *(const float4*)(xlp);
    float4 v1 = *(const float4*)(xlp + 4);
    float p, tv;
    tv = v0.x + r0.x; tv = tv > 0.f ? tv : 0.2f * tv; p  = tv * a0.x;
    tv = v0.y + r0.y; tv = tv > 0.f ? tv : 0.2f * tv; p += tv * a0.y;
    tv = v0.z + r0.z; tv = tv > 0.f ? tv : 0.2f * tv; p += tv * a0.z;
    tv = v0.w + r0.w; tv = tv > 0.f ? tv : 0.2f * tv; p += tv * a0.w;
    tv = v1.x + r1.x; tv = tv > 0.f ? tv : 0.2f * tv; p += tv * a1.x;
    tv = v1.y + r1.y; tv = tv > 0.f ? tv : 0.2f * tv; p += tv * a1.y;
    tv = v1.z + r1.z; tv = tv > 0.f ? tv : 0.2f * tv; p += tv * a1.z;
    tv = v1.w + r1.w; tv = tv > 0.f ? tv : 0.2f * tv; p += tv * a1.w;
    p += __shfl_xor(p, 1); p += __shfl_xor(p, 2); p += __shfl_xor(p, 4);
    float nm = fmaxf(m, p);
    float w  = __expf(p - nm);
    float sc = __expf(m - nm);
    den = den * sc + w;
    acc[0] = acc[0] * sc + w * v0.x;
    acc[1] = acc[1] * sc + w * v0.y;
    acc[2] = acc[2] * sc + w * v0.z;
    acc[3] = acc[3] * sc + w * v0.w;
    acc[4] = acc[4] * sc + w * v1.x;
    acc[5] = acc[5] * sc + w * v1.y;
    acc[6] = acc[6] * sc + w * v1.z;
    acc[7] = acc[7] * sc + w * v1.w;
    m = nm;
  }
  float inv = 1.f / den;
  float4 b0v = *(const float4*)(bias + base);
  float4 b1v = *(const float4*)(bias + base + 4);
  float o[8];
  o[0] = acc[0] * inv + b0v.x; o[1] = acc[1] * inv + b0v.y;
  o[2] = acc[2] * inv + b0v.z; o[3] = acc[3] * inv + b0v.w;
  o[4] = acc[4] * inv + b1v.x; o[5] = acc[5] * inv + b1v.y;
  o[6] = acc[6] * inv + b1v.z; o[7] = acc[7] * inv + b1v.w;
#pragma unroll
  for (int k = 0; k < 8; k++) o[k] = o[k] > 0.f ? o[k] : 0.f;
  float* op = out + (size_t)d * HHD + base;
  *(float4*)(op)     = make_float4(o[0], o[1], o[2], o[3]);
  *(float4*)(op + 4) = make_float4(o[4], o[5], o[6], o[7]);
  float4 w0 = *(const float4*)(pw + base);
  float4 w1 = *(const float4*)(pw + base + 4);
  float sdot = o[0]*w0.x + o[1]*w0.y + o[2]*w0.z + o[3]*w0.w
             + o[4]*w1.x + o[5]*w1.y + o[6]*w1.z + o[7]*w1.w;
#pragma unroll
  for (int off = 32; off > 0; off >>= 1) sdot += __shfl_xor(sdot, off);
  if (lane == 0) xls[d] = sdot;
}

// ---------------- Stage 2 fused: heads=1, dim 64 ----------------
__global__ __launch_bounds__(256) void gat2_fused(const int* __restrict__ rowptr,
                                                  const int* __restrict__ csr_eid,
                                                  const int* __restrict__ src,
                                                  const int* __restrict__ newid,
                                                  const float* __restrict__ xl,
                                                  const float* __restrict__ xr,
                                                  const float* __restrict__ att,
                                                  const float* __restrict__ bias,
                                                  const float* __restrict__ pw,
                                                  float* __restrict__ out,
                                                  float* __restrict__ xls, int n) {
  int lane = threadIdx.x & 63;
  long long t = (long long)blockIdx.x * blockDim.x + threadIdx.x;
  int d = (int)(t >> 6);
  if (d >= n) return;
  float av = att[lane];
  float rr = xr[(size_t)d * HIDD + lane];
  float m = -INFINITY, den = 0.f, acc = 0.f;
  int b0 = rowptr[d], b1 = rowptr[d + 1];
  for (int j = b0; j < b1; j++) {
    int eid = csr_eid[j];
    int s = (eid < E_EDGES) ? newid[src[eid]] : eid - E_EDGES;
    float v = xl[(size_t)s * HIDD + lane];
    float tv = v + rr; tv = tv > 0.f ? tv : 0.2f * tv;
    float p = tv * av;
#pragma unroll
    for (int off = 32; off > 0; off >>= 1) p += __shfl_xor(p, off);
    float nm = fmaxf(m, p);
    float w  = __expf(p - nm);
    float sc = __expf(m - nm);
    den = den * sc + w;
    acc = acc * sc + w * v;
    m = nm;
  }
  float o = acc / den + bias[lane];
  o = o > 0.f ? o : 0.f;
  out[(size_t)d * HIDD + lane] = o;
  float sdot = o * pw[lane];
#pragma unroll
  for (int off = 32; off > 0; off >>= 1) sdot += __shfl_xor(sdot, off);
  if (lane == 0) xls[d] = sdot;
}

// ---------------- pool scoring: single-pass online softmax + tanh ----------------
__global__ __launch_bounds__(256) void pool_score(const int* __restrict__ rowptr,
                                                  const int* __restrict__ csr_eid,
                                                  const int* __restrict__ src,
                                                  const int* __restrict__ newid_map,
                                                  const float* __restrict__ xls,
                                                  const float* __restrict__ asrc,
                                                  const float* __restrict__ adst,
                                                  const float* __restrict__ bias,
                                                  const float* __restrict__ sel,
                                                  float* __restrict__ score, int n) {
  int d = blockIdx.x * blockDim.x + threadIdx.x;
  if (d >= n) return;
  float as = asrc[0], ad = adst[0];
  float ar = xls[d] * ad;
  int b0 = rowptr[d], b1 = rowptr[d + 1];
  float m = -INFINITY, den = 0.f, num = 0.f;
  for (int j = b0; j < b1; j++) {
    int eid = csr_eid[j];
    int s = (eid < E_EDGES) ? (newid_map ? newid_map[src[eid]] : src[eid]) : eid - E_EDGES;
    float xs = xls[s];
    float e = xs * as + ar;
    e = e > 0.f ? e : 0.2f * e;
    float nm = fmaxf(m, e);
    float scv = __expf(m - nm);
    float ex = __expf(e - nm);
    den = den * scv + ex;
    num = num * scv + ex * xs;
    m = nm;
  }
  float attn = num / den + bias[0];
  float sv = sel[0];
  score[d] = tanhf(attn * sv / fabsf(sv));
}

// ---------------- top-k via 2D-grid rank counting ----------------
#define TK_CHUNK 512
__global__ __launch_bounds__(256) void topk_count(const float* __restrict__ score,
                                                  int* __restrict__ rank, int n) {
  __shared__ float sc[TK_CHUNK];
  int i = blockIdx.x * 256 + threadIdx.x;
  int base = blockIdx.y * TK_CHUNK;
  int cnt = min(TK_CHUNK, n - base);
  for (int j = threadIdx.x; j < cnt; j += 256) sc[j] = score[base + j];
  __syncthreads();
  if (i >= n) return;
  float si = score[i];
  int r = 0;
  for (int j = 0; j < cnt; j++) {
    float sj = sc[j];
    r += (sj > si) || ((sj == si) && ((base + j) < i));
  }
  if (r) atomicAdd(&rank[i], r);
}

__global__ void topk_assign(const int* __restrict__ rank, int* __restrict__ newid,
                            int* __restrict__ perm, int n, int k) {
  int i = blockIdx.x * blockDim.x + threadIdx.x;
  if (i < n) {
    int r = rank[i];
    newid[i] = (r < k) ? r : -1;
    if (r < k) perm[r] = i;
  }
}

// column max/sum over pooled rows, gathered via perm with score scaling
__global__ __launch_bounds__(256) void col_pool(const float* __restrict__ X,
                                                const int* __restrict__ perm,
                                                const float* __restrict__ scalev,
                                                int rows, int C,
                                                float* __restrict__ omax, float* __restrict__ osum) {
  int tid = threadIdx.x;
  float mx[2] = {-INFINITY, -INFINITY};
  float sm[2] = {0.f, 0.f};
  int nseg = (C + 255) / 256;
  int rpb = (rows + gridDim.x - 1) / gridDim.x;
  int rbeg = blockIdx.x * rpb;
  int rend = min(rows, rbeg + rpb);
  for (int r = rbeg; r < rend; r++) {
    int orow = perm[r];
    float sc = scalev[orow];
    const float* row = X + (size_t)orow * C;
    for (int sg = 0; sg < nseg; sg++) {
      int c = sg * 256 + tid;
      if (c < C) {
        float v = row[c] * sc;
        mx[sg] = fmaxf(mx[sg], v);
        sm[sg] += v;
      }
    }
  }
  if (rbeg < rend) {
    for (int sg = 0; sg < nseg; sg++) {
      int c = sg * 256 + tid;
      if (c < C) { atomicMaxF(&omax[c], mx[sg]); atomicAdd(&osum[c], sm[sg]); }
    }
  }
}

// ---------------- MLP head, parallelized ----------------
__global__ void z_build(const float* __restrict__ x1max, const float* __restrict__ x1sum,
                        const float* __restrict__ g2max, const float* __restrict__ g2sum,
                        float* __restrict__ z) {
  int i = blockIdx.x * blockDim.x + threadIdx.x;
  if (i >= 1024) return;
  float xv = (i < 512) ? x1max[i] : x1sum[i - 512] * (1.f / K1N);
  float gv = (i < 512) ? g2max[i & 63] : g2sum[i & 63] * (1.f / K2N);
  z[i] = xv + gv;
}

template<int NIN>
__global__ __launch_bounds__(256) void mlp_layer(const float* __restrict__ in,
                                                 const float* __restrict__ w,
                                                 const float* __restrict__ b,
                                                 float* __restrict__ out, int nout) {
  __shared__ float red[16][17];
  int t = threadIdx.x;
  int jl = t & 15, ch = t >> 4;
  int j = blockIdx.x * 16 + jl;
  constexpr int CH = NIN / 16;
  float p = 0.f;
  for (int k = ch * CH; k < (ch + 1) * CH; k++) p += in[k] * w[(size_t)k * nout + j];
  red[ch][jl] = p;
  __syncthreads();
  if (t < 16) {
    float s = b[blockIdx.x * 16 + t];
    for (int c = 0; c < 16; c++) s += red[c][t];
    out[blockIdx.x * 16 + t] = s > 0.f ? s : 0.f;
  }
}

__global__ __launch_bounds__(128) void mlp_final(const float* __restrict__ z3,
                                                 const float* __restrict__ w4,
                                                 const float* __restrict__ b4,
                                                 float* __restrict__ out) {
  int t = threadIdx.x;
  float v = z3[t];
  float p0 = v * w4[2 * t], p1 = v * w4[2 * t + 1];
#pragma unroll
  for (int off = 32; off > 0; off >>= 1) {
    p0 += __shfl_xor(p0, off);
    p1 += __shfl_xor(p1, off);
  }
  __shared__ float s0[2], s1[2];
  if ((t & 63) == 0) { s0[t >> 6] = p0; s1[t >> 6] = p1; }
  __syncthreads();
  if (t == 0) {
    float l0 = s0[0] + s0[1] + b4[0], l1 = s1[0] + s1[1] + b4[1];
    float m = fmaxf(l0, l1);
    float e0 = __expf(l0 - m), e1 = __expf(l1 - m);
    float s = e0 + e1;
    out[0] = l0; out[1] = l1;
    out[2] = e0 / s; out[3] = e1 / s;
  }
}

extern "C" void kernel_launch(void* const* d_in, const int* in_sizes, int n_in,
                              void* d_out, int out_size, void* d_ws, size_t ws_size,
                              hipStream_t stream) {
  const float* x       = (const float*)d_in[0];
  const int*   ei      = (const int*)d_in[1];
  const float* g1_wl   = (const float*)d_in[2];
  const float* g1_wr   = (const float*)d_in[3];
  const float* g1_att  = (const float*)d_in[4];
  const float* g1_b    = (const float*)d_in[5];
  const float* p1_w    = (const float*)d_in[6];
  const float* p1_asrc = (const float*)d_in[7];
  const float* p1_adst = (const float*)d_in[8];
  const float* p1_b    = (const float*)d_in[9];
  const float* p1_sel  = (const float*)d_in[10];
  const float* g2_wl   = (const float*)d_in[11];
  const float* g2_wr   = (const float*)d_in[12];
  const float* g2_att  = (const float*)d_in[13];
  const float* g2_b    = (const float*)d_in[14];
  const float* p2_w    = (const float*)d_in[15];
  const float* p2_asrc = (const float*)d_in[16];
  const float* p2_adst = (const float*)d_in[17];
  const float* p2_b    = (const float*)d_in[18];
  const float* p2_sel  = (const float*)d_in[19];
  const float* l1_w    = (const float*)d_in[20];
  const float* l1_b    = (const float*)d_in[21];
  const float* l2_w    = (const float*)d_in[22];
  const float* l2_b    = (const float*)d_in[23];
  const float* l3_w    = (const float*)d_in[24];
  const float* l3_b    = (const float*)d_in[25];
  const float* l4_w    = (const float*)d_in[26];
  const float* l4_b    = (const float*)d_in[27];

  const int* src = ei;
  const int* dst = ei + E_EDGES;

  if (ws_size < (size_t)33440000 * 4) return;
  float* ws  = (float*)d_ws;
  float* xl1 = ws;                 // 10.24M
  float* xr1 = ws + 10240000;      // 10.24M; later arena2
  float* h1  = ws + 20480000;      // 10.24M
  float* aux = ws + 30720000;      // 2.72M persistent

  int*   csr_eid1 = (int*)aux;               // 340000
  int*   rowptr1  = (int*)(aux + 340000);    // 20001
  int*   deg1     = (int*)(aux + 360064);    // 20000 (deg -> cursor)
  int*   rank1    = (int*)(aux + 380064);    // 20000
  int*   newid1   = (int*)(aux + 400064);    // 20000
  float* xls1     = aux + 420064;            // 20000
  float* scr1     = aux + 440064;            // 20000
  float* pools    = aux + 460064;            // 1152: x1max|x1sum|g2max|g2sum
  float* x1max    = pools;
  float* x1sum    = pools + 512;
  float* g2max    = pools + 1024;
  float* g2sum    = pools + 1088;
  int*   perm1    = (int*)(aux + 461248);    // 20000
  float* z        = aux + 481248;            // 1024
  float* z1       = aux + 482272;            // 512
  float* z2       = aux + 482784;            // 256
  float* z3       = aux + 483040;            // 128

  float* a2 = xr1;                           // stage-2 arena (free after gat1_fused)
  float* xl2      = a2;                      // 960000
  float* xr2      = a2 + 960000;             // 960000
  float* h2       = a2 + 1920000;            // 960000
  int*   csr_eid2 = (int*)(a2 + 2880000);    // 335000
  int*   rowptr2  = (int*)(a2 + 3215000);    // 15001
  int*   deg2     = (int*)(a2 + 3230016);    // 15000  (deg2+rank2 contiguous)
  int*   rank2    = (int*)(a2 + 3245016);    // 15000
  int*   newid2   = (int*)(a2 + 3260016);    // 15000
  float* xls2     = a2 + 3275016;            // 15000
  float* scr2     = a2 + 3290016;            // 15000
  int*   perm2    = (int*)(a2 + 3305016);    // 15000

  dim3 b256(256);
  const int E1 = E_EDGES + N_NODES;   // 340000
  const int E2 = E_EDGES + K1N;       // 335000

  // ---- init + CSR1 ----
  init_all<<<cdiv(2 * N_NODES + 1152, 256), b256, 0, stream>>>(deg1, rank1, pools);
  deg_count<<<cdiv(E1, 256), b256, 0, stream>>>(src, dst, nullptr, deg1, N_NODES);
  scan_excl<<<1, 1024, 0, stream>>>(deg1, rowptr1, deg1, N_NODES);
  csr_scatter<<<cdiv(E1, 256), b256, 0, stream>>>(src, dst, nullptr, deg1, csr_eid1, N_NODES);

  // ---- Stage 1: fused dual GEMM (Wl|Wr) + fused GAT ----
  gemm_dual<128, 128, 16, 8, 8><<<dim3(2 * HHD / 128, cdiv(N_NODES, 128)), b256, 0, stream>>>(
      x, nullptr, nullptr, g1_wl, g1_wr, xl1, xr1, N_NODES, HHD, DIN);
  gat1_fused<<<cdiv((long long)N_NODES * 64, 256), b256, 0, stream>>>(
      rowptr1, csr_eid1, src, xl1, xr1, g1_att, g1_b, p1_w, h1, xls1);

  // ---- Pool 1 ----
  pool_score<<<cdiv(N_NODES, 256), b256, 0, stream>>>(rowptr1, csr_eid1, src, nullptr, xls1,
                                                      p1_asrc, p1_adst, p1_b, p1_sel, scr1, N_NODES);
  topk_count<<<dim3(cdiv(N_NODES, 256), cdiv(N_NODES, TK_CHUNK)), b256, 0, stream>>>(scr1, rank1, N_NODES);
  topk_assign<<<cdiv(N_NODES, 256), b256, 0, stream>>>(rank1, newid1, perm1, N_NODES, K1N);
  col_pool<<<128, b256, 0, stream>>>(h1, perm1, scr1, K1N, HHD, x1max, x1sum);

  // ---- CSR2 + Stage 2 (A rows gathered via perm1, scaled by scr1) ----
  fill_i32<<<cdiv(30000, 256), b256, 0, stream>>>(deg2, 0, 30000);  // deg2 + rank2
  deg_count<<<cdiv(E2, 256), b256, 0, stream>>>(src, dst, newid1, deg2, K1N);
  scan_excl<<<1, 1024, 0, stream>>>(deg2, rowptr2, deg2, K1N);
  csr_scatter<<<cdiv(E2, 256), b256, 0, stream>>>(src, dst, newid1, deg2, csr_eid2, K1N);

  gemm_dual<64, 64, 32, 4, 4><<<dim3(2 * HIDD / 64, cdiv(K1N, 64)), b256, 0, stream>>>(
      h1, perm1, scr1, g2_wl, g2_wr, xl2, xr2, K1N, HIDD, HHD);
  gat2_fused<<<cdiv((long long)K1N * 64, 256), b256, 0, stream>>>(
      rowptr2, csr_eid2, src, newid1, xl2, xr2, g2_att, g2_b, p2_w, h2, xls2, K1N);

  // ---- Pool 2 ----
  pool_score<<<cdiv(K1N, 256), b256, 0, stream>>>(rowptr2, csr_eid2, src, newid1, xls2,
                                                  p2_asrc, p2_adst, p2_b, p2_sel, scr2, K1N);
  topk_count<<<dim3(cdiv(K1N, 256), cdiv(K1N, TK_CHUNK)), b256, 0, stream>>>(scr2, rank2, K1N);
  topk_assign<<<cdiv(K1N, 256), b256, 0, stream>>>(rank2, newid2, perm2, K1N, K2N);
  col_pool<<<128, b256, 0, stream>>>(h2, perm2, scr2, K2N, HIDD, g2max, g2sum);

  // ---- MLP head ----
  z_build<<<4, b256, 0, stream>>>(x1max, x1sum, g2max, g2sum, z);
  mlp_layer<1024><<<32, b256, 0, stream>>>(z, l1_w, l1_b, z1, 512);
  mlp_layer<512><<<16, b256, 0, stream>>>(z1, l2_w, l2_b, z2, 256);
  mlp_layer<256><<<8, b256, 0, stream>>>(z2, l3_w, l3_b, z3, 128);
  mlp_final<<<1, 128, 0, stream>>>(z3, l4_w, l4_b, (float*)d_out);
}